// Round 10
// baseline (235.859 us; speedup 1.0000x reference)
//
#include <hip/hip_runtime.h>

// ---- problem constants (B,H0,W0,C)=(16,56,56,96), NH=3, WS=7, SS=3, HID=384, NCL=128 ----
#define NB 16
#define NHH 56
#define NWW 56
#define NC 96
#define NL (NHH*NWW)          // 3136
#define NTOK (NB*NL)          // 50176
#define WSZ 7
#define NT 49                 // tokens per window
#define SSH 3
#define NWIN 1024             // 16 * 8 * 8
#define HDIM 32
#define HID_ 384
#define NCL_ 128
#define NLIT 768
#define EPS_ 1e-6f
#define LOG_EPS -13.815510558f

typedef unsigned short u16;
typedef unsigned int   u32;
typedef __attribute__((ext_vector_type(8))) short short8;   // 8 bf16 (4 VGPRs)
typedef __attribute__((ext_vector_type(4))) float f32x4;    // MFMA C/D

__device__ __forceinline__ float us2f(u16 u) {
  union { u32 u; float f; } x; x.u = ((u32)u) << 16; return x.f;
}
__device__ __forceinline__ u16 f2us(float f) {   // RNE float->bf16
  union { float f; u32 u; } x; x.f = f;
  u32 lsb = (x.u >> 16) & 1u;
  return (u16)((x.u + 0x7fffu + lsb) >> 16);
}
__device__ __forceinline__ float sigmoidf_(float x) { return 1.f / (1.f + __expf(-x)); }

// ---------------- K0: build bf16 constants ----------------
__global__ __launch_bounds__(256) void k0_prep(const float* __restrict__ tm_inc,
                                               const float* __restrict__ pin_w,
                                               const float* __restrict__ tm_out,
                                               const float* __restrict__ qkv_w,
                                               const float* __restrict__ proj_w,
                                               u16* __restrict__ maskb,
                                               u16* __restrict__ pinwb,
                                               u16* __restrict__ tmoT,
                                               u16* __restrict__ qkvwb,
                                               u16* __restrict__ projwb) {
  int idx = blockIdx.x * 256 + threadIdx.x;
  if (idx < NCL_ * NLIT)
    maskb[idx] = (tm_inc[idx] > 0.f) ? (u16)0x3F80 : (u16)0;
  if (idx < HID_ * NC)
    pinwb[idx] = f2us(pin_w[idx]);
  if (idx < NC * NCL_) {
    int c = idx / NCL_, k = idx - c * NCL_;
    tmoT[idx] = f2us(tm_out[(size_t)k * NC + c]);
  }
  if (idx < 3 * NC * NC)
    qkvwb[idx] = f2us(qkv_w[idx]);
  if (idx < NC * NC)
    projwb[idx] = f2us(proj_w[idx]);
}

// ---------------- K2: LN1 + window gather + MFMA attention + proj + residual scatter ----------------
// One block = one window. 4 waves; wave w owns query rows 16w..16w+15. (unchanged from round 9)
__global__ __launch_bounds__(256) void k2_attn(const float* __restrict__ x,
                                               const float* __restrict__ n1g,
                                               const float* __restrict__ n1b,
                                               const u16* __restrict__ qkvwb,
                                               const float* __restrict__ qkv_b,
                                               const u16* __restrict__ projwb,
                                               const float* __restrict__ proj_b,
                                               float* __restrict__ x1) {
  __shared__ __align__(16) u16 syb[64 * 104];
  __shared__ __align__(16) u16 sq [64 * 104];
  __shared__ __align__(16) u16 sk [64 * 104];
  __shared__ __align__(16) u16 svT[96 * 72];
  __shared__ __align__(16) u16 sp [4 * 16 * 72];
  const int tid  = threadIdx.x;
  const int wave = tid >> 6;
  const int lane = tid & 63;
  const int l16  = lane & 15;
  const int quad = lane >> 4;
  const int win  = blockIdx.x;
  const int t0   = wave * 16;
  const int bb = win >> 6, wl = win & 63;
  const int hbase = (wl >> 3) * WSZ, wbase = (wl & 7) * WSZ;

  // ---- LN1 head: 4 threads per token; gather from x with inverse global roll ----
  {
    const int t = tid >> 2, s = tid & 3;
    if (t < NT) {
      int hp = hbase + t / WSZ, wp = wbase + t % WSZ;
      int h = hp + SSH; if (h >= NHH) h -= NHH;
      int w = wp + SSH; if (w >= NWW) w -= NWW;
      const float* xp = x + ((size_t)bb * NL + (size_t)h * NWW + w) * NC;
      float4 v[6];
      float sum = 0.f;
      #pragma unroll
      for (int k = 0; k < 6; ++k) {
        v[k] = *reinterpret_cast<const float4*>(xp + s * 4 + k * 16);
        sum += v[k].x + v[k].y + v[k].z + v[k].w;
      }
      sum += __shfl_xor(sum, 1); sum += __shfl_xor(sum, 2);
      float mean = sum * (1.f / 96.f);
      float ssq = 0.f;
      #pragma unroll
      for (int k = 0; k < 6; ++k) {
        float d0 = v[k].x - mean, d1 = v[k].y - mean;
        float d2 = v[k].z - mean, d3 = v[k].w - mean;
        ssq += d0 * d0 + d1 * d1 + d2 * d2 + d3 * d3;
      }
      ssq += __shfl_xor(ssq, 1); ssq += __shfl_xor(ssq, 2);
      float rstd = rsqrtf(ssq * (1.f / 96.f) + 1e-5f);
      #pragma unroll
      for (int k = 0; k < 6; ++k) {
        int c = s * 4 + k * 16;
        const float4 g4 = *reinterpret_cast<const float4*>(n1g + c);
        const float4 b4 = *reinterpret_cast<const float4*>(n1b + c);
        syb[t * 104 + c + 0] = f2us((v[k].x - mean) * rstd * g4.x + b4.x);
        syb[t * 104 + c + 1] = f2us((v[k].y - mean) * rstd * g4.y + b4.y);
        syb[t * 104 + c + 2] = f2us((v[k].z - mean) * rstd * g4.z + b4.z);
        syb[t * 104 + c + 3] = f2us((v[k].w - mean) * rstd * g4.w + b4.w);
      }
    } else {
      #pragma unroll
      for (int k = 0; k < 6; ++k) {
        int c = s * 4 + k * 16;
        syb[t * 104 + c + 0] = 0; syb[t * 104 + c + 1] = 0;
        syb[t * 104 + c + 2] = 0; syb[t * 104 + c + 3] = 0;
      }
    }
  }
  __syncthreads();

  // ---- QKV: M=64, N=288 (18 tiles), K=96 (3 steps); depth-4 B-frag ring ----
  {
    short8 afr[3];
    #pragma unroll
    for (int ks = 0; ks < 3; ++ks)
      afr[ks] = *reinterpret_cast<const short8*>(&syb[(t0 + l16) * 104 + quad * 8 + ks * 32]);
    short8 rb[4][3];
    #pragma unroll
    for (int p = 0; p < 4; ++p)
      #pragma unroll
      for (int ks = 0; ks < 3; ++ks)
        rb[p][ks] = *reinterpret_cast<const short8*>(
            qkvwb + (size_t)(p * 16 + l16) * NC + quad * 8 + ks * 32);
    #pragma unroll
    for (int nt = 0; nt < 18; ++nt) {
      const int n0 = nt * 16;
      const float bias = qkv_b[n0 + l16];
      short8 b0 = rb[nt & 3][0], b1 = rb[nt & 3][1], b2 = rb[nt & 3][2];
      if (nt + 4 < 18) {
        #pragma unroll
        for (int ks = 0; ks < 3; ++ks)
          rb[nt & 3][ks] = *reinterpret_cast<const short8*>(
              qkvwb + (size_t)((nt + 4) * 16 + l16) * NC + quad * 8 + ks * 32);
      }
      f32x4 acc = {0.f, 0.f, 0.f, 0.f};
      acc = __builtin_amdgcn_mfma_f32_16x16x32_bf16(afr[0], b0, acc, 0, 0, 0);
      acc = __builtin_amdgcn_mfma_f32_16x16x32_bf16(afr[1], b1, acc, 0, 0, 0);
      acc = __builtin_amdgcn_mfma_f32_16x16x32_bf16(afr[2], b2, acc, 0, 0, 0);
      const int part = nt / 6;                 // 0=q 1=k 2=v
      const int oc = n0 - part * 96 + l16;
      if (part < 2) {
        u16* dst = (part == 0) ? sq : sk;
        #pragma unroll
        for (int r = 0; r < 4; ++r)
          dst[(t0 + quad * 4 + r) * 104 + oc] = f2us(acc[r] + bias);
      } else {
        #pragma unroll
        for (int r = 0; r < 4; ++r)
          svT[oc * 72 + (t0 + quad * 4 + r)] = f2us(acc[r] + bias);
      }
    }
  }
  __syncthreads();

  // ---- per head: scores -> in-register softmax -> PV (all wave-private) ----
  u16* spw = sp + wave * 16 * 72;
  const float sscale = 0.17677669529663687f;
  for (int h = 0; h < 3; ++h) {
    const int d0 = h * HDIM;
    short8 qf = *reinterpret_cast<const short8*>(&sq[(t0 + l16) * 104 + d0 + quad * 8]);
    f32x4 s[4];
    #pragma unroll
    for (int nt = 0; nt < 4; ++nt) {
      short8 kf = *reinterpret_cast<const short8*>(&sk[(nt * 16 + l16) * 104 + d0 + quad * 8]);
      f32x4 a = {0.f, 0.f, 0.f, 0.f};
      s[nt] = __builtin_amdgcn_mfma_f32_16x16x32_bf16(qf, kf, a, 0, 0, 0);
    }
    #pragma unroll
    for (int nt = 0; nt < 4; ++nt)
      #pragma unroll
      for (int r = 0; r < 4; ++r) s[nt][r] *= sscale;
    if (l16 >= 1) {                       // key col 48+l16 >= 49 -> mask
      #pragma unroll
      for (int r = 0; r < 4; ++r) s[3][r] = -1e30f;
    }
    #pragma unroll
    for (int r = 0; r < 4; ++r) {
      float m = fmaxf(fmaxf(s[0][r], s[1][r]), fmaxf(s[2][r], s[3][r]));
      #pragma unroll
      for (int off = 8; off > 0; off >>= 1) m = fmaxf(m, __shfl_xor(m, off, 16));
      float e0 = __expf(s[0][r] - m), e1 = __expf(s[1][r] - m);
      float e2 = __expf(s[2][r] - m), e3 = __expf(s[3][r] - m);
      float sum = e0 + e1 + e2 + e3;
      #pragma unroll
      for (int off = 8; off > 0; off >>= 1) sum += __shfl_xor(sum, off, 16);
      float inv = 1.f / sum;
      const int row = quad * 4 + r;
      spw[row * 72 +      l16] = f2us(e0 * inv);
      spw[row * 72 + 16 + l16] = f2us(e1 * inv);
      spw[row * 72 + 32 + l16] = f2us(e2 * inv);
      spw[row * 72 + 48 + l16] = f2us(e3 * inv);
    }
    short8 pa[2];
    pa[0] = *reinterpret_cast<const short8*>(&spw[l16 * 72 + quad * 8]);
    pa[1] = *reinterpret_cast<const short8*>(&spw[l16 * 72 + 32 + quad * 8]);
    #pragma unroll
    for (int nt = 0; nt < 2; ++nt) {
      const int c0 = d0 + nt * 16;
      f32x4 acc = {0.f, 0.f, 0.f, 0.f};
      #pragma unroll
      for (int ks = 0; ks < 2; ++ks) {
        short8 vb = *reinterpret_cast<const short8*>(&svT[(c0 + l16) * 72 + ks * 32 + quad * 8]);
        acc = __builtin_amdgcn_mfma_f32_16x16x32_bf16(pa[ks], vb, acc, 0, 0, 0);
      }
      #pragma unroll
      for (int r = 0; r < 4; ++r)
        syb[(t0 + quad * 4 + r) * 104 + c0 + l16] = f2us(acc[r]);
    }
  }

  // ---- proj: N=96 (6 tiles), K=96 (3 steps); prefetched residuals + depth-2 B ring ----
  {
    short8 aa[3];
    #pragma unroll
    for (int ks = 0; ks < 3; ++ks)
      aa[ks] = *reinterpret_cast<const short8*>(&syb[(t0 + l16) * 104 + quad * 8 + ks * 32]);

    size_t tokr[4]; bool tval[4];
    #pragma unroll
    for (int r = 0; r < 4; ++r) {
      const int t = t0 + quad * 4 + r;
      tval[r] = (t < NT);
      int rr = t / WSZ + SSH; if (rr >= WSZ) rr -= WSZ;
      int qq = t % WSZ + SSH; if (qq >= WSZ) qq -= WSZ;
      tokr[r] = (size_t)bb * NL + (size_t)(hbase + rr) * NWW + (wbase + qq);
    }
    float xv[6][4];
    #pragma unroll
    for (int nt = 0; nt < 6; ++nt)
      #pragma unroll
      for (int r = 0; r < 4; ++r)
        xv[nt][r] = tval[r] ? x[tokr[r] * NC + nt * 16 + l16] : 0.f;

    short8 pbr[2][3];
    #pragma unroll
    for (int ks = 0; ks < 3; ++ks)
      pbr[0][ks] = *reinterpret_cast<const short8*>(
          projwb + (size_t)l16 * NC + quad * 8 + ks * 32);
    #pragma unroll
    for (int nt = 0; nt < 6; ++nt) {
      const int n0 = nt * 16;
      const float pb = proj_b[n0 + l16];
      short8 b0 = pbr[nt & 1][0], b1 = pbr[nt & 1][1], b2 = pbr[nt & 1][2];
      if (nt + 1 < 6) {
        #pragma unroll
        for (int ks = 0; ks < 3; ++ks)
          pbr[(nt + 1) & 1][ks] = *reinterpret_cast<const short8*>(
              projwb + (size_t)((nt + 1) * 16 + l16) * NC + quad * 8 + ks * 32);
      }
      f32x4 acc = {0.f, 0.f, 0.f, 0.f};
      acc = __builtin_amdgcn_mfma_f32_16x16x32_bf16(aa[0], b0, acc, 0, 0, 0);
      acc = __builtin_amdgcn_mfma_f32_16x16x32_bf16(aa[1], b1, acc, 0, 0, 0);
      acc = __builtin_amdgcn_mfma_f32_16x16x32_bf16(aa[2], b2, acc, 0, 0, 0);
      #pragma unroll
      for (int r = 0; r < 4; ++r) {
        if (tval[r])
          x1[tokr[r] * NC + n0 + l16] = xv[nt][r] + acc[r] + pb;
      }
    }
  }
}

// ---------------- K4: double-LN + TM-FFN via MFMA; 32 tokens/block, 8 waves, 2 lit-passes ----------------
// LDS: lit 16x776 (24,832 B) + union(szb 32x104 / claT 32x136) (8,704 B) = 33,536 B -> 4 blocks/CU
// -> 32 waves/CU (100% occupancy). Literals via softplus: log(sig(a)) = a - sp, log(1-sig(a)) = -sp.
__global__ __launch_bounds__(512) void k4_ffn(const float* __restrict__ x1,
                                              const float* __restrict__ g2,
                                              const float* __restrict__ b2,
                                              const float* __restrict__ gf,
                                              const float* __restrict__ bf,
                                              const u16* __restrict__ pinwb,
                                              const float* __restrict__ pin_b,
                                              const u16* __restrict__ maskb,
                                              const u16* __restrict__ tmoT,
                                              const float* __restrict__ gate,
                                              float* __restrict__ out) {
  __shared__ __align__(16) u16 lit[16 * 776];   // lit for the current 16-token pass
  __shared__ __align__(16) u16 su[32 * 136];    // union: szb (32x104, dies early) / claT (32x136)
  u16* szb  = su;
  u16* claT = su;
  const int tid  = threadIdx.x;
  const int wave = tid >> 6;
  const int lane = tid & 63;
  const int l16  = lane & 15;
  const int quad = lane >> 4;
  const size_t tok0 = (size_t)blockIdx.x * 32;

  // ---- LN(LN(x1)) head: 16 lanes per token, 6 channels each (float2 x 3) ----
  {
    const int t = tid >> 4, s = tid & 15;
    const float* xp = x1 + (tok0 + t) * NC;
    float2 v[3];
    float sum = 0.f;
    #pragma unroll
    for (int k = 0; k < 3; ++k) {
      const int c = s * 2 + k * 32;
      v[k] = *reinterpret_cast<const float2*>(xp + c);
      sum += v[k].x + v[k].y;
    }
    #pragma unroll
    for (int off = 8; off > 0; off >>= 1) sum += __shfl_xor(sum, off, 16);
    const float mean = sum * (1.f / 96.f);
    float ssq = 0.f;
    #pragma unroll
    for (int k = 0; k < 3; ++k) {
      float d0 = v[k].x - mean, d1 = v[k].y - mean;
      ssq += d0 * d0 + d1 * d1;
    }
    #pragma unroll
    for (int off = 8; off > 0; off >>= 1) ssq += __shfl_xor(ssq, off, 16);
    const float rstd = rsqrtf(ssq * (1.f / 96.f) + 1e-5f);
    float tv[6];
    float sum2 = 0.f;
    #pragma unroll
    for (int k = 0; k < 3; ++k) {
      const int c = s * 2 + k * 32;
      const float2 gg = *reinterpret_cast<const float2*>(g2 + c);
      const float2 bb = *reinterpret_cast<const float2*>(b2 + c);
      tv[2 * k]     = (v[k].x - mean) * rstd * gg.x + bb.x;
      tv[2 * k + 1] = (v[k].y - mean) * rstd * gg.y + bb.y;
      sum2 += tv[2 * k] + tv[2 * k + 1];
    }
    #pragma unroll
    for (int off = 8; off > 0; off >>= 1) sum2 += __shfl_xor(sum2, off, 16);
    const float mean2 = sum2 * (1.f / 96.f);
    float ssq2 = 0.f;
    #pragma unroll
    for (int k = 0; k < 3; ++k) {
      float d0 = tv[2 * k] - mean2, d1 = tv[2 * k + 1] - mean2;
      ssq2 += d0 * d0 + d1 * d1;
    }
    #pragma unroll
    for (int off = 8; off > 0; off >>= 1) ssq2 += __shfl_xor(ssq2, off, 16);
    const float rstd2 = rsqrtf(ssq2 * (1.f / 96.f) + 1e-5f);
    #pragma unroll
    for (int k = 0; k < 3; ++k) {
      const int c = s * 2 + k * 32;
      const float2 gg = *reinterpret_cast<const float2*>(gf + c);
      const float2 bb = *reinterpret_cast<const float2*>(bf + c);
      u16 lo = f2us((tv[2 * k]     - mean2) * rstd2 * gg.x + bb.x);
      u16 hi = f2us((tv[2 * k + 1] - mean2) * rstd2 * gg.y + bb.y);
      *reinterpret_cast<u32*>(&szb[t * 104 + c]) = (u32)lo | ((u32)hi << 16);
    }
  }
  __syncthreads();   // B1: szb complete

  const float gv = sigmoidf_(gate[0]);

  // A-frags for both pin M-tiles (szb dies after these loads; claT may then reuse su)
  short8 a_pin[2][3];
  #pragma unroll
  for (int mt = 0; mt < 2; ++mt)
    #pragma unroll
    for (int ks = 0; ks < 3; ++ks)
      a_pin[mt][ks] = *reinterpret_cast<const short8*>(
          &szb[(mt * 16 + l16) * 104 + quad * 8 + ks * 32]);

  float pbias[3];
  #pragma unroll
  for (int i = 0; i < 3; ++i) pbias[i] = pin_b[(wave * 3 + i) * 16 + l16];

  #pragma unroll
  for (int pass = 0; pass < 2; ++pass) {
    // ---- pin gemm (M-tile `pass`): wave w -> N-tiles [3w,3w+3); depth-2 B ring ----
    {
      short8 pb[2][3];
      #pragma unroll
      for (int ks = 0; ks < 3; ++ks)
        pb[0][ks] = *reinterpret_cast<const short8*>(
            pinwb + (size_t)(wave * 3 * 16 + l16) * NC + quad * 8 + ks * 32);
      #pragma unroll
      for (int i = 0; i < 3; ++i) {
        short8 b0 = pb[i & 1][0], b1 = pb[i & 1][1], b2 = pb[i & 1][2];
        if (i + 1 < 3) {
          const int n1 = (wave * 3 + i + 1) * 16;
          #pragma unroll
          for (int ks = 0; ks < 3; ++ks)
            pb[(i + 1) & 1][ks] = *reinterpret_cast<const short8*>(
                pinwb + (size_t)(n1 + l16) * NC + quad * 8 + ks * 32);
        }
        f32x4 acc = {0.f, 0.f, 0.f, 0.f};
        acc = __builtin_amdgcn_mfma_f32_16x16x32_bf16(a_pin[pass][0], b0, acc, 0, 0, 0);
        acc = __builtin_amdgcn_mfma_f32_16x16x32_bf16(a_pin[pass][1], b1, acc, 0, 0, 0);
        acc = __builtin_amdgcn_mfma_f32_16x16x32_bf16(a_pin[pass][2], b2, acc, 0, 0, 0);
        const int o = (wave * 3 + i) * 16 + l16;
        const float pbv = pbias[i];
        #pragma unroll
        for (int r = 0; r < 4; ++r) {
          const float a = acc[r] + pbv;
          const float sp = fmaxf(a, 0.f) + __logf(1.f + __expf(-fabsf(a)));
          const int t = quad * 4 + r;
          lit[t * 776 + o]       = f2us(fmaxf(a - sp, LOG_EPS));
          lit[t * 776 + 384 + o] = f2us(fmaxf(-sp, LOG_EPS));
        }
      }
    }
    __syncthreads();   // lit(pass) complete (also fences a_pin reads vs claT writes)

    // ---- clause gemm (16 tokens of this pass): wave w -> clause tile w; depth-4 B ring ----
    {
      const int ct = wave;
      const u16* bp0 = maskb + (size_t)(ct * 16 + l16) * NLIT + quad * 8;
      short8 rb0[4];
      #pragma unroll
      for (int p = 0; p < 4; ++p)
        rb0[p] = *reinterpret_cast<const short8*>(bp0 + p * 32);
      f32x4 c00 = {0.f, 0.f, 0.f, 0.f};
      #pragma unroll
      for (int ks = 0; ks < 24; ++ks) {
        const int k0 = ks * 32 + quad * 8;
        short8 a0 = *reinterpret_cast<const short8*>(&lit[l16 * 776 + k0]);
        short8 b0 = rb0[ks & 3];
        if (ks + 4 < 24)
          rb0[ks & 3] = *reinterpret_cast<const short8*>(bp0 + (ks + 4) * 32);
        c00 = __builtin_amdgcn_mfma_f32_16x16x32_bf16(a0, b0, c00, 0, 0, 0);
      }
      #pragma unroll
      for (int r = 0; r < 4; ++r) {
        const int t = pass * 16 + quad * 4 + r;
        claT[t * 136 + ct * 16 + l16] = f2us(__expf(c00[r]));
      }
    }
    __syncthreads();   // claT(pass) complete; lit free for next pass
  }

  // ---- logits = cla @ tm_out; 6 N-tiles over waves 0-5; fused blend epilogue ----
  if (wave < 6) {
    const int nt = wave;
    f32x4 acc0 = {0.f, 0.f, 0.f, 0.f}, acc1 = {0.f, 0.f, 0.f, 0.f};
    #pragma unroll
    for (int ks = 0; ks < 4; ++ks) {
      const int k0 = ks * 32 + quad * 8;
      short8 a0 = *reinterpret_cast<const short8*>(&claT[l16 * 136 + k0]);
      short8 a1 = *reinterpret_cast<const short8*>(&claT[(16 + l16) * 136 + k0]);
      short8 b = *reinterpret_cast<const short8*>(
          tmoT + (size_t)(nt * 16 + l16) * NCL_ + k0);
      acc0 = __builtin_amdgcn_mfma_f32_16x16x32_bf16(a0, b, acc0, 0, 0, 0);
      acc1 = __builtin_amdgcn_mfma_f32_16x16x32_bf16(a1, b, acc1, 0, 0, 0);
    }
    const int c = nt * 16 + l16;
    #pragma unroll
    for (int r = 0; r < 4; ++r) {
      const int ta = quad * 4 + r, tb = 16 + quad * 4 + r;
      float lg0 = acc0[r], lg1 = acc1[r];
      out[(tok0 + ta) * NC + c] =
          x1[(tok0 + ta) * NC + c] + gv * lg0 + (1.f - gv) * sigmoidf_(lg0);
      out[(tok0 + tb) * NC + c] =
          x1[(tok0 + tb) * NC + c] + gv * lg1 + (1.f - gv) * sigmoidf_(lg1);
    }
  }
}

extern "C" void kernel_launch(void* const* d_in, const int* in_sizes, int n_in,
                              void* d_out, int out_size, void* d_ws, size_t ws_size,
                              hipStream_t stream) {
  (void)in_sizes; (void)n_in; (void)out_size; (void)ws_size;
  const float* x      = (const float*)d_in[0];
  const float* n1g    = (const float*)d_in[1];
  const float* n1b    = (const float*)d_in[2];
  const float* qkv_w  = (const float*)d_in[3];
  const float* qkv_b  = (const float*)d_in[4];
  const float* proj_w = (const float*)d_in[5];
  const float* proj_b = (const float*)d_in[6];
  const float* n2g    = (const float*)d_in[7];
  const float* n2b    = (const float*)d_in[8];
  const float* fng    = (const float*)d_in[9];
  const float* fnb    = (const float*)d_in[10];
  const float* pin_w  = (const float*)d_in[11];
  const float* pin_b  = (const float*)d_in[12];
  const float* tm_inc = (const float*)d_in[13];
  const float* tm_out = (const float*)d_in[14];
  const float* gate   = (const float*)d_in[15];

  float* x1 = (float*)d_ws;                         // NTOK*96 f32
  u16* maskb = (u16*)(x1 + (size_t)NTOK * NC);      // 128*768 bf16
  u16* pinwb = maskb + NCL_ * NLIT;                 // 384*96 bf16
  u16* tmoT  = pinwb + HID_ * NC;                   // 96*128 bf16
  u16* qkvwb = tmoT + NC * NCL_;                    // 288*96 bf16
  u16* projwb= qkvwb + 3 * NC * NC;                 // 96*96 bf16

  hipLaunchKernelGGL(k0_prep, dim3(384), dim3(256), 0, stream,
                     tm_inc, pin_w, tm_out, qkv_w, proj_w, maskb, pinwb, tmoT, qkvwb, projwb);
  hipLaunchKernelGGL(k2_attn, dim3(NWIN), dim3(256), 0, stream,
                     x, n1g, n1b, qkvwb, qkv_b, projwb, proj_b, x1);
  hipLaunchKernelGGL(k4_ffn, dim3(NTOK / 32), dim3(512), 0, stream,
                     x1, n2g, n2b, fng, fnb, pinwb, pin_b, maskb, tmoT, gate, (float*)d_out);
}

// Round 11
// 204.846 us; speedup vs baseline: 1.1514x; 1.1514x over previous
//
#include <hip/hip_runtime.h>

// ---- problem constants (B,H0,W0,C)=(16,56,56,96), NH=3, WS=7, SS=3, HID=384, NCL=128 ----
#define NB 16
#define NHH 56
#define NWW 56
#define NC 96
#define NL (NHH*NWW)          // 3136
#define NTOK (NB*NL)          // 50176
#define WSZ 7
#define NT 49                 // tokens per window
#define SSH 3
#define NWIN 1024             // 16 * 8 * 8
#define HDIM 32
#define HID_ 384
#define NCL_ 128
#define NLIT 768
#define EPS_ 1e-6f
#define LOG_EPS -13.815510558f

typedef unsigned short u16;
typedef unsigned int   u32;
typedef __attribute__((ext_vector_type(8))) short short8;   // 8 bf16 (4 VGPRs)
typedef __attribute__((ext_vector_type(4))) float f32x4;    // MFMA C/D

__device__ __forceinline__ float us2f(u16 u) {
  union { u32 u; float f; } x; x.u = ((u32)u) << 16; return x.f;
}
__device__ __forceinline__ u16 f2us(float f) {   // RNE float->bf16
  union { float f; u32 u; } x; x.f = f;
  u32 lsb = (x.u >> 16) & 1u;
  return (u16)((x.u + 0x7fffu + lsb) >> 16);
}
__device__ __forceinline__ float sigmoidf_(float x) { return 1.f / (1.f + __expf(-x)); }

// ---------------- K0: build bf16 constants ----------------
// maskb is stored J-INTERLEAVED: j' = 2*o for the "y" literal, 2*o+1 for the "1-y" literal.
// The clause dot-product is invariant under this permutation as long as lit uses the same order.
__global__ __launch_bounds__(256) void k0_prep(const float* __restrict__ tm_inc,
                                               const float* __restrict__ pin_w,
                                               const float* __restrict__ tm_out,
                                               const float* __restrict__ qkv_w,
                                               const float* __restrict__ proj_w,
                                               u16* __restrict__ maskb,
                                               u16* __restrict__ pinwb,
                                               u16* __restrict__ tmoT,
                                               u16* __restrict__ qkvwb,
                                               u16* __restrict__ projwb) {
  int idx = blockIdx.x * 256 + threadIdx.x;
  if (idx < NCL_ * NLIT) {
    int k = idx / NLIT, j = idx - k * NLIT;
    int o   = (j < HID_) ? j : (j - HID_);
    int pos = (j < HID_) ? (2 * o) : (2 * o + 1);
    maskb[(size_t)k * NLIT + pos] = (tm_inc[idx] > 0.f) ? (u16)0x3F80 : (u16)0;
  }
  if (idx < HID_ * NC)
    pinwb[idx] = f2us(pin_w[idx]);
  if (idx < NC * NCL_) {
    int c = idx / NCL_, k = idx - c * NCL_;
    tmoT[idx] = f2us(tm_out[(size_t)k * NC + c]);
  }
  if (idx < 3 * NC * NC)
    qkvwb[idx] = f2us(qkv_w[idx]);
  if (idx < NC * NC)
    projwb[idx] = f2us(proj_w[idx]);
}

// ---------------- K2: LN1 + window gather + MFMA attention + proj + residual scatter ----------------
// One block = one window. 4 waves; wave w owns query rows 16w..16w+15. (unchanged from round 9)
__global__ __launch_bounds__(256) void k2_attn(const float* __restrict__ x,
                                               const float* __restrict__ n1g,
                                               const float* __restrict__ n1b,
                                               const u16* __restrict__ qkvwb,
                                               const float* __restrict__ qkv_b,
                                               const u16* __restrict__ projwb,
                                               const float* __restrict__ proj_b,
                                               float* __restrict__ x1) {
  __shared__ __align__(16) u16 syb[64 * 104];
  __shared__ __align__(16) u16 sq [64 * 104];
  __shared__ __align__(16) u16 sk [64 * 104];
  __shared__ __align__(16) u16 svT[96 * 72];
  __shared__ __align__(16) u16 sp [4 * 16 * 72];
  const int tid  = threadIdx.x;
  const int wave = tid >> 6;
  const int lane = tid & 63;
  const int l16  = lane & 15;
  const int quad = lane >> 4;
  const int win  = blockIdx.x;
  const int t0   = wave * 16;
  const int bb = win >> 6, wl = win & 63;
  const int hbase = (wl >> 3) * WSZ, wbase = (wl & 7) * WSZ;

  // ---- LN1 head: 4 threads per token; gather from x with inverse global roll ----
  {
    const int t = tid >> 2, s = tid & 3;
    if (t < NT) {
      int hp = hbase + t / WSZ, wp = wbase + t % WSZ;
      int h = hp + SSH; if (h >= NHH) h -= NHH;
      int w = wp + SSH; if (w >= NWW) w -= NWW;
      const float* xp = x + ((size_t)bb * NL + (size_t)h * NWW + w) * NC;
      float4 v[6];
      float sum = 0.f;
      #pragma unroll
      for (int k = 0; k < 6; ++k) {
        v[k] = *reinterpret_cast<const float4*>(xp + s * 4 + k * 16);
        sum += v[k].x + v[k].y + v[k].z + v[k].w;
      }
      sum += __shfl_xor(sum, 1); sum += __shfl_xor(sum, 2);
      float mean = sum * (1.f / 96.f);
      float ssq = 0.f;
      #pragma unroll
      for (int k = 0; k < 6; ++k) {
        float d0 = v[k].x - mean, d1 = v[k].y - mean;
        float d2 = v[k].z - mean, d3 = v[k].w - mean;
        ssq += d0 * d0 + d1 * d1 + d2 * d2 + d3 * d3;
      }
      ssq += __shfl_xor(ssq, 1); ssq += __shfl_xor(ssq, 2);
      float rstd = rsqrtf(ssq * (1.f / 96.f) + 1e-5f);
      #pragma unroll
      for (int k = 0; k < 6; ++k) {
        int c = s * 4 + k * 16;
        const float4 g4 = *reinterpret_cast<const float4*>(n1g + c);
        const float4 b4 = *reinterpret_cast<const float4*>(n1b + c);
        syb[t * 104 + c + 0] = f2us((v[k].x - mean) * rstd * g4.x + b4.x);
        syb[t * 104 + c + 1] = f2us((v[k].y - mean) * rstd * g4.y + b4.y);
        syb[t * 104 + c + 2] = f2us((v[k].z - mean) * rstd * g4.z + b4.z);
        syb[t * 104 + c + 3] = f2us((v[k].w - mean) * rstd * g4.w + b4.w);
      }
    } else {
      #pragma unroll
      for (int k = 0; k < 6; ++k) {
        int c = s * 4 + k * 16;
        syb[t * 104 + c + 0] = 0; syb[t * 104 + c + 1] = 0;
        syb[t * 104 + c + 2] = 0; syb[t * 104 + c + 3] = 0;
      }
    }
  }
  __syncthreads();

  // ---- QKV: M=64, N=288 (18 tiles), K=96 (3 steps); depth-4 B-frag ring ----
  {
    short8 afr[3];
    #pragma unroll
    for (int ks = 0; ks < 3; ++ks)
      afr[ks] = *reinterpret_cast<const short8*>(&syb[(t0 + l16) * 104 + quad * 8 + ks * 32]);
    short8 rb[4][3];
    #pragma unroll
    for (int p = 0; p < 4; ++p)
      #pragma unroll
      for (int ks = 0; ks < 3; ++ks)
        rb[p][ks] = *reinterpret_cast<const short8*>(
            qkvwb + (size_t)(p * 16 + l16) * NC + quad * 8 + ks * 32);
    #pragma unroll
    for (int nt = 0; nt < 18; ++nt) {
      const int n0 = nt * 16;
      const float bias = qkv_b[n0 + l16];
      short8 b0 = rb[nt & 3][0], b1 = rb[nt & 3][1], b2 = rb[nt & 3][2];
      if (nt + 4 < 18) {
        #pragma unroll
        for (int ks = 0; ks < 3; ++ks)
          rb[nt & 3][ks] = *reinterpret_cast<const short8*>(
              qkvwb + (size_t)((nt + 4) * 16 + l16) * NC + quad * 8 + ks * 32);
      }
      f32x4 acc = {0.f, 0.f, 0.f, 0.f};
      acc = __builtin_amdgcn_mfma_f32_16x16x32_bf16(afr[0], b0, acc, 0, 0, 0);
      acc = __builtin_amdgcn_mfma_f32_16x16x32_bf16(afr[1], b1, acc, 0, 0, 0);
      acc = __builtin_amdgcn_mfma_f32_16x16x32_bf16(afr[2], b2, acc, 0, 0, 0);
      const int part = nt / 6;                 // 0=q 1=k 2=v
      const int oc = n0 - part * 96 + l16;
      if (part < 2) {
        u16* dst = (part == 0) ? sq : sk;
        #pragma unroll
        for (int r = 0; r < 4; ++r)
          dst[(t0 + quad * 4 + r) * 104 + oc] = f2us(acc[r] + bias);
      } else {
        #pragma unroll
        for (int r = 0; r < 4; ++r)
          svT[oc * 72 + (t0 + quad * 4 + r)] = f2us(acc[r] + bias);
      }
    }
  }
  __syncthreads();

  // ---- per head: scores -> in-register softmax -> PV (all wave-private) ----
  u16* spw = sp + wave * 16 * 72;
  const float sscale = 0.17677669529663687f;
  for (int h = 0; h < 3; ++h) {
    const int d0 = h * HDIM;
    short8 qf = *reinterpret_cast<const short8*>(&sq[(t0 + l16) * 104 + d0 + quad * 8]);
    f32x4 s[4];
    #pragma unroll
    for (int nt = 0; nt < 4; ++nt) {
      short8 kf = *reinterpret_cast<const short8*>(&sk[(nt * 16 + l16) * 104 + d0 + quad * 8]);
      f32x4 a = {0.f, 0.f, 0.f, 0.f};
      s[nt] = __builtin_amdgcn_mfma_f32_16x16x32_bf16(qf, kf, a, 0, 0, 0);
    }
    #pragma unroll
    for (int nt = 0; nt < 4; ++nt)
      #pragma unroll
      for (int r = 0; r < 4; ++r) s[nt][r] *= sscale;
    if (l16 >= 1) {                       // key col 48+l16 >= 49 -> mask
      #pragma unroll
      for (int r = 0; r < 4; ++r) s[3][r] = -1e30f;
    }
    #pragma unroll
    for (int r = 0; r < 4; ++r) {
      float m = fmaxf(fmaxf(s[0][r], s[1][r]), fmaxf(s[2][r], s[3][r]));
      #pragma unroll
      for (int off = 8; off > 0; off >>= 1) m = fmaxf(m, __shfl_xor(m, off, 16));
      float e0 = __expf(s[0][r] - m), e1 = __expf(s[1][r] - m);
      float e2 = __expf(s[2][r] - m), e3 = __expf(s[3][r] - m);
      float sum = e0 + e1 + e2 + e3;
      #pragma unroll
      for (int off = 8; off > 0; off >>= 1) sum += __shfl_xor(sum, off, 16);
      float inv = 1.f / sum;
      const int row = quad * 4 + r;
      spw[row * 72 +      l16] = f2us(e0 * inv);
      spw[row * 72 + 16 + l16] = f2us(e1 * inv);
      spw[row * 72 + 32 + l16] = f2us(e2 * inv);
      spw[row * 72 + 48 + l16] = f2us(e3 * inv);
    }
    short8 pa[2];
    pa[0] = *reinterpret_cast<const short8*>(&spw[l16 * 72 + quad * 8]);
    pa[1] = *reinterpret_cast<const short8*>(&spw[l16 * 72 + 32 + quad * 8]);
    #pragma unroll
    for (int nt = 0; nt < 2; ++nt) {
      const int c0 = d0 + nt * 16;
      f32x4 acc = {0.f, 0.f, 0.f, 0.f};
      #pragma unroll
      for (int ks = 0; ks < 2; ++ks) {
        short8 vb = *reinterpret_cast<const short8*>(&svT[(c0 + l16) * 72 + ks * 32 + quad * 8]);
        acc = __builtin_amdgcn_mfma_f32_16x16x32_bf16(pa[ks], vb, acc, 0, 0, 0);
      }
      #pragma unroll
      for (int r = 0; r < 4; ++r)
        syb[(t0 + quad * 4 + r) * 104 + c0 + l16] = f2us(acc[r]);
    }
  }

  // ---- proj: N=96 (6 tiles), K=96 (3 steps); prefetched residuals + depth-2 B ring ----
  {
    short8 aa[3];
    #pragma unroll
    for (int ks = 0; ks < 3; ++ks)
      aa[ks] = *reinterpret_cast<const short8*>(&syb[(t0 + l16) * 104 + quad * 8 + ks * 32]);

    size_t tokr[4]; bool tval[4];
    #pragma unroll
    for (int r = 0; r < 4; ++r) {
      const int t = t0 + quad * 4 + r;
      tval[r] = (t < NT);
      int rr = t / WSZ + SSH; if (rr >= WSZ) rr -= WSZ;
      int qq = t % WSZ + SSH; if (qq >= WSZ) qq -= WSZ;
      tokr[r] = (size_t)bb * NL + (size_t)(hbase + rr) * NWW + (wbase + qq);
    }
    float xv[6][4];
    #pragma unroll
    for (int nt = 0; nt < 6; ++nt)
      #pragma unroll
      for (int r = 0; r < 4; ++r)
        xv[nt][r] = tval[r] ? x[tokr[r] * NC + nt * 16 + l16] : 0.f;

    short8 pbr[2][3];
    #pragma unroll
    for (int ks = 0; ks < 3; ++ks)
      pbr[0][ks] = *reinterpret_cast<const short8*>(
          projwb + (size_t)l16 * NC + quad * 8 + ks * 32);
    #pragma unroll
    for (int nt = 0; nt < 6; ++nt) {
      const int n0 = nt * 16;
      const float pb = proj_b[n0 + l16];
      short8 b0 = pbr[nt & 1][0], b1 = pbr[nt & 1][1], b2 = pbr[nt & 1][2];
      if (nt + 1 < 6) {
        #pragma unroll
        for (int ks = 0; ks < 3; ++ks)
          pbr[(nt + 1) & 1][ks] = *reinterpret_cast<const short8*>(
              projwb + (size_t)((nt + 1) * 16 + l16) * NC + quad * 8 + ks * 32);
      }
      f32x4 acc = {0.f, 0.f, 0.f, 0.f};
      acc = __builtin_amdgcn_mfma_f32_16x16x32_bf16(aa[0], b0, acc, 0, 0, 0);
      acc = __builtin_amdgcn_mfma_f32_16x16x32_bf16(aa[1], b1, acc, 0, 0, 0);
      acc = __builtin_amdgcn_mfma_f32_16x16x32_bf16(aa[2], b2, acc, 0, 0, 0);
      #pragma unroll
      for (int r = 0; r < 4; ++r) {
        if (tval[r])
          x1[tokr[r] * NC + n0 + l16] = xv[nt][r] + acc[r] + pb;
      }
    }
  }
}

// ---------------- K4: double-LN + TM-FFN via MFMA; 32 tokens/block, 8 waves (512 thr) ----------------
// r9 structure (single pin pass, clause with 2-M-tile B-reuse) + softplus literals +
// packed u32 lit writes in j-interleaved layout (stride 778, conflict-free) + szb/claT union.
// LDS: lit 32x778 (49,792 B) + union(szb 32x104 / claT 32x140) (8,960 B) = 58,752 B -> 2 blocks/CU.
__global__ __launch_bounds__(512) void k4_ffn(const float* __restrict__ x1,
                                              const float* __restrict__ g2,
                                              const float* __restrict__ b2,
                                              const float* __restrict__ gf,
                                              const float* __restrict__ bf,
                                              const u16* __restrict__ pinwb,
                                              const float* __restrict__ pin_b,
                                              const u16* __restrict__ maskb,
                                              const u16* __restrict__ tmoT,
                                              const float* __restrict__ gate,
                                              float* __restrict__ out) {
  __shared__ __align__(16) u16 lit[32 * 778];   // bf16 log-literals, j-interleaved
  __shared__ __align__(16) u16 su[32 * 140];    // union: szb (32x104, dies early) / claT (32x140)
  u16* szb  = su;
  u16* claT = su;
  const int tid  = threadIdx.x;
  const int wave = tid >> 6;
  const int lane = tid & 63;
  const int l16  = lane & 15;
  const int quad = lane >> 4;
  const size_t tok0 = (size_t)blockIdx.x * 32;

  // ---- LN(LN(x1)) head: 16 lanes per token, 6 channels each (float2 x 3) ----
  {
    const int t = tid >> 4, s = tid & 15;
    const float* xp = x1 + (tok0 + t) * NC;
    float2 v[3];
    float sum = 0.f;
    #pragma unroll
    for (int k = 0; k < 3; ++k) {
      const int c = s * 2 + k * 32;
      v[k] = *reinterpret_cast<const float2*>(xp + c);
      sum += v[k].x + v[k].y;
    }
    #pragma unroll
    for (int off = 8; off > 0; off >>= 1) sum += __shfl_xor(sum, off, 16);
    const float mean = sum * (1.f / 96.f);
    float ssq = 0.f;
    #pragma unroll
    for (int k = 0; k < 3; ++k) {
      float d0 = v[k].x - mean, d1 = v[k].y - mean;
      ssq += d0 * d0 + d1 * d1;
    }
    #pragma unroll
    for (int off = 8; off > 0; off >>= 1) ssq += __shfl_xor(ssq, off, 16);
    const float rstd = rsqrtf(ssq * (1.f / 96.f) + 1e-5f);
    float tv[6];
    float sum2 = 0.f;
    #pragma unroll
    for (int k = 0; k < 3; ++k) {
      const int c = s * 2 + k * 32;
      const float2 gg = *reinterpret_cast<const float2*>(g2 + c);
      const float2 bb = *reinterpret_cast<const float2*>(b2 + c);
      tv[2 * k]     = (v[k].x - mean) * rstd * gg.x + bb.x;
      tv[2 * k + 1] = (v[k].y - mean) * rstd * gg.y + bb.y;
      sum2 += tv[2 * k] + tv[2 * k + 1];
    }
    #pragma unroll
    for (int off = 8; off > 0; off >>= 1) sum2 += __shfl_xor(sum2, off, 16);
    const float mean2 = sum2 * (1.f / 96.f);
    float ssq2 = 0.f;
    #pragma unroll
    for (int k = 0; k < 3; ++k) {
      float d0 = tv[2 * k] - mean2, d1 = tv[2 * k + 1] - mean2;
      ssq2 += d0 * d0 + d1 * d1;
    }
    #pragma unroll
    for (int off = 8; off > 0; off >>= 1) ssq2 += __shfl_xor(ssq2, off, 16);
    const float rstd2 = rsqrtf(ssq2 * (1.f / 96.f) + 1e-5f);
    #pragma unroll
    for (int k = 0; k < 3; ++k) {
      const int c = s * 2 + k * 32;
      const float2 gg = *reinterpret_cast<const float2*>(gf + c);
      const float2 bb = *reinterpret_cast<const float2*>(bf + c);
      u16 lo = f2us((tv[2 * k]     - mean2) * rstd2 * gg.x + bb.x);
      u16 hi = f2us((tv[2 * k + 1] - mean2) * rstd2 * gg.y + bb.y);
      *reinterpret_cast<u32*>(&szb[t * 104 + c]) = (u32)lo | ((u32)hi << 16);
    }
  }
  __syncthreads();   // B1: szb complete

  const float gv = sigmoidf_(gate[0]);

  // A-frags for both pin M-tiles (szb dies after these loads; claT reuses su after B2)
  short8 a_pin[2][3];
  #pragma unroll
  for (int mt = 0; mt < 2; ++mt)
    #pragma unroll
    for (int ks = 0; ks < 3; ++ks)
      a_pin[mt][ks] = *reinterpret_cast<const short8*>(
          &szb[(mt * 16 + l16) * 104 + quad * 8 + ks * 32]);

  // ---- pin gemm: wave w -> N-tiles [3w,3w+3); depth-2 B ring; 2 MFMA per B-frag;
  //      softplus literals, one packed u32 LDS write per (token, o) pair ----
  {
    float pbias[3];
    #pragma unroll
    for (int i = 0; i < 3; ++i) pbias[i] = pin_b[(wave * 3 + i) * 16 + l16];
    short8 pb[2][3];
    #pragma unroll
    for (int ks = 0; ks < 3; ++ks)
      pb[0][ks] = *reinterpret_cast<const short8*>(
          pinwb + (size_t)(wave * 3 * 16 + l16) * NC + quad * 8 + ks * 32);
    #pragma unroll
    for (int i = 0; i < 3; ++i) {
      short8 b0 = pb[i & 1][0], b1 = pb[i & 1][1], b2 = pb[i & 1][2];
      if (i + 1 < 3) {
        const int n1 = (wave * 3 + i + 1) * 16;
        #pragma unroll
        for (int ks = 0; ks < 3; ++ks)
          pb[(i + 1) & 1][ks] = *reinterpret_cast<const short8*>(
              pinwb + (size_t)(n1 + l16) * NC + quad * 8 + ks * 32);
      }
      f32x4 acc0 = {0.f, 0.f, 0.f, 0.f}, acc1 = {0.f, 0.f, 0.f, 0.f};
      acc0 = __builtin_amdgcn_mfma_f32_16x16x32_bf16(a_pin[0][0], b0, acc0, 0, 0, 0);
      acc1 = __builtin_amdgcn_mfma_f32_16x16x32_bf16(a_pin[1][0], b0, acc1, 0, 0, 0);
      acc0 = __builtin_amdgcn_mfma_f32_16x16x32_bf16(a_pin[0][1], b1, acc0, 0, 0, 0);
      acc1 = __builtin_amdgcn_mfma_f32_16x16x32_bf16(a_pin[1][1], b1, acc1, 0, 0, 0);
      acc0 = __builtin_amdgcn_mfma_f32_16x16x32_bf16(a_pin[0][2], b2, acc0, 0, 0, 0);
      acc1 = __builtin_amdgcn_mfma_f32_16x16x32_bf16(a_pin[1][2], b2, acc1, 0, 0, 0);
      const int o2 = ((wave * 3 + i) * 16 + l16) * 2;   // j-interleaved offset
      const float pbv = pbias[i];
      #pragma unroll
      for (int r = 0; r < 4; ++r) {
        const float a0 = acc0[r] + pbv;
        const float sp0 = fmaxf(a0, 0.f) + __logf(1.f + __expf(-fabsf(a0)));
        const u16 la0 = f2us(fmaxf(a0 - sp0, LOG_EPS));
        const u16 lb0 = f2us(fmaxf(-sp0, LOG_EPS));
        const float a1 = acc1[r] + pbv;
        const float sp1 = fmaxf(a1, 0.f) + __logf(1.f + __expf(-fabsf(a1)));
        const u16 la1 = f2us(fmaxf(a1 - sp1, LOG_EPS));
        const u16 lb1 = f2us(fmaxf(-sp1, LOG_EPS));
        const int ta = quad * 4 + r, tb = 16 + quad * 4 + r;
        *reinterpret_cast<u32*>(&lit[ta * 778 + o2]) = (u32)la0 | ((u32)lb0 << 16);
        *reinterpret_cast<u32*>(&lit[tb * 778 + o2]) = (u32)la1 | ((u32)lb1 << 16);
      }
    }
  }
  __syncthreads();   // B2: lit complete (also fences a_pin/szb reads vs claT writes)

  // ---- clause gemm: wave w -> clause tile w; depth-4 B ring; 2 MFMA per B-frag ----
  {
    const int ct = wave;
    const u16* bp0 = maskb + (size_t)(ct * 16 + l16) * NLIT + quad * 8;
    short8 rb0[4];
    #pragma unroll
    for (int p = 0; p < 4; ++p)
      rb0[p] = *reinterpret_cast<const short8*>(bp0 + p * 32);
    f32x4 c00 = {0.f, 0.f, 0.f, 0.f}, c10 = {0.f, 0.f, 0.f, 0.f};
    #pragma unroll
    for (int ks = 0; ks < 24; ++ks) {
      const int k0 = ks * 32 + quad * 8;
      short8 a0 = *reinterpret_cast<const short8*>(&lit[l16 * 778 + k0]);
      short8 a1 = *reinterpret_cast<const short8*>(&lit[(16 + l16) * 778 + k0]);
      short8 b0 = rb0[ks & 3];
      if (ks + 4 < 24)
        rb0[ks & 3] = *reinterpret_cast<const short8*>(bp0 + (ks + 4) * 32);
      c00 = __builtin_amdgcn_mfma_f32_16x16x32_bf16(a0, b0, c00, 0, 0, 0);
      c10 = __builtin_amdgcn_mfma_f32_16x16x32_bf16(a1, b0, c10, 0, 0, 0);
    }
    #pragma unroll
    for (int r = 0; r < 4; ++r) {
      const int ta = quad * 4 + r, tb = 16 + quad * 4 + r;
      claT[ta * 140 + ct * 16 + l16] = f2us(__expf(c00[r]));
      claT[tb * 140 + ct * 16 + l16] = f2us(__expf(c10[r]));
    }
  }
  __syncthreads();   // B3: claT complete

  // ---- logits = cla @ tm_out; 6 N-tiles over waves 0-5; fused blend epilogue ----
  if (wave < 6) {
    const int nt = wave;
    f32x4 acc0 = {0.f, 0.f, 0.f, 0.f}, acc1 = {0.f, 0.f, 0.f, 0.f};
    #pragma unroll
    for (int ks = 0; ks < 4; ++ks) {
      const int k0 = ks * 32 + quad * 8;
      short8 a0 = *reinterpret_cast<const short8*>(&claT[l16 * 140 + k0]);
      short8 a1 = *reinterpret_cast<const short8*>(&claT[(16 + l16) * 140 + k0]);
      short8 b = *reinterpret_cast<const short8*>(
          tmoT + (size_t)(nt * 16 + l16) * NCL_ + k0);
      acc0 = __builtin_amdgcn_mfma_f32_16x16x32_bf16(a0, b, acc0, 0, 0, 0);
      acc1 = __builtin_amdgcn_mfma_f32_16x16x32_bf16(a1, b, acc1, 0, 0, 0);
    }
    const int c = nt * 16 + l16;
    #pragma unroll
    for (int r = 0; r < 4; ++r) {
      const int ta = quad * 4 + r, tb = 16 + quad * 4 + r;
      float lg0 = acc0[r], lg1 = acc1[r];
      out[(tok0 + ta) * NC + c] =
          x1[(tok0 + ta) * NC + c] + gv * lg0 + (1.f - gv) * sigmoidf_(lg0);
      out[(tok0 + tb) * NC + c] =
          x1[(tok0 + tb) * NC + c] + gv * lg1 + (1.f - gv) * sigmoidf_(lg1);
    }
  }
}

extern "C" void kernel_launch(void* const* d_in, const int* in_sizes, int n_in,
                              void* d_out, int out_size, void* d_ws, size_t ws_size,
                              hipStream_t stream) {
  (void)in_sizes; (void)n_in; (void)out_size; (void)ws_size;
  const float* x      = (const float*)d_in[0];
  const float* n1g    = (const float*)d_in[1];
  const float* n1b    = (const float*)d_in[2];
  const float* qkv_w  = (const float*)d_in[3];
  const float* qkv_b  = (const float*)d_in[4];
  const float* proj_w = (const float*)d_in[5];
  const float* proj_b = (const float*)d_in[6];
  const float* n2g    = (const float*)d_in[7];
  const float* n2b    = (const float*)d_in[8];
  const float* fng    = (const float*)d_in[9];
  const float* fnb    = (const float*)d_in[10];
  const float* pin_w  = (const float*)d_in[11];
  const float* pin_b  = (const float*)d_in[12];
  const float* tm_inc = (const float*)d_in[13];
  const float* tm_out = (const float*)d_in[14];
  const float* gate   = (const float*)d_in[15];

  float* x1 = (float*)d_ws;                         // NTOK*96 f32
  u16* maskb = (u16*)(x1 + (size_t)NTOK * NC);      // 128*768 bf16 (j-interleaved)
  u16* pinwb = maskb + NCL_ * NLIT;                 // 384*96 bf16
  u16* tmoT  = pinwb + HID_ * NC;                   // 96*128 bf16
  u16* qkvwb = tmoT + NC * NCL_;                    // 288*96 bf16
  u16* projwb= qkvwb + 3 * NC * NC;                 // 96*96 bf16

  hipLaunchKernelGGL(k0_prep, dim3(384), dim3(256), 0, stream,
                     tm_inc, pin_w, tm_out, qkv_w, proj_w, maskb, pinwb, tmoT, qkvwb, projwb);
  hipLaunchKernelGGL(k2_attn, dim3(NWIN), dim3(256), 0, stream,
                     x, n1g, n1b, qkvwb, qkv_b, projwb, proj_b, x1);
  hipLaunchKernelGGL(k4_ffn, dim3(NTOK / 32), dim3(512), 0, stream,
                     x1, n2g, n2b, fng, fnb, pinwb, pin_b, maskb, tmoT, gate, (float*)d_out);
}

// Round 12
// 196.649 us; speedup vs baseline: 1.1994x; 1.0417x over previous
//
#include <hip/hip_runtime.h>

// ---- problem constants (B,H0,W0,C)=(16,56,56,96), NH=3, WS=7, SS=3, HID=384, NCL=128 ----
#define NB 16
#define NHH 56
#define NWW 56
#define NC 96
#define NL (NHH*NWW)          // 3136
#define NTOK (NB*NL)          // 50176
#define WSZ 7
#define NT 49                 // tokens per window
#define SSH 3
#define NWIN 1024             // 16 * 8 * 8
#define HDIM 32
#define HID_ 384
#define NCL_ 128
#define NLIT 768
#define EPS_ 1e-6f
#define LOG_EPS -13.815510558f

typedef unsigned short u16;
typedef unsigned int   u32;
typedef __attribute__((ext_vector_type(8))) short short8;   // 8 bf16 (4 VGPRs)
typedef __attribute__((ext_vector_type(4))) float f32x4;    // MFMA C/D

__device__ __forceinline__ float us2f(u16 u) {
  union { u32 u; float f; } x; x.u = ((u32)u) << 16; return x.f;
}
__device__ __forceinline__ u16 f2us(float f) {   // RNE float->bf16
  union { float f; u32 u; } x; x.f = f;
  u32 lsb = (x.u >> 16) & 1u;
  return (u16)((x.u + 0x7fffu + lsb) >> 16);
}
__device__ __forceinline__ float sigmoidf_(float x) { return 1.f / (1.f + __expf(-x)); }

// ---------------- K0: build bf16 constants ----------------
__global__ __launch_bounds__(256) void k0_prep(const float* __restrict__ tm_inc,
                                               const float* __restrict__ pin_w,
                                               const float* __restrict__ tm_out,
                                               const float* __restrict__ qkv_w,
                                               const float* __restrict__ proj_w,
                                               u16* __restrict__ maskb,
                                               u16* __restrict__ pinwb,
                                               u16* __restrict__ tmoT,
                                               u16* __restrict__ qkvwb,
                                               u16* __restrict__ projwb) {
  int idx = blockIdx.x * 256 + threadIdx.x;
  if (idx < NCL_ * NLIT)
    maskb[idx] = (tm_inc[idx] > 0.f) ? (u16)0x3F80 : (u16)0;
  if (idx < HID_ * NC)
    pinwb[idx] = f2us(pin_w[idx]);
  if (idx < NC * NCL_) {
    int c = idx / NCL_, k = idx - c * NCL_;
    tmoT[idx] = f2us(tm_out[(size_t)k * NC + c]);
  }
  if (idx < 3 * NC * NC)
    qkvwb[idx] = f2us(qkv_w[idx]);
  if (idx < NC * NC)
    projwb[idx] = f2us(proj_w[idx]);
}

// ---------------- K2: LN1 + window gather + MFMA attention + proj + residual scatter ----------------
// One block = one window. 4 waves; wave w owns query rows 16w..16w+15. (unchanged from round 9)
__global__ __launch_bounds__(256) void k2_attn(const float* __restrict__ x,
                                               const float* __restrict__ n1g,
                                               const float* __restrict__ n1b,
                                               const u16* __restrict__ qkvwb,
                                               const float* __restrict__ qkv_b,
                                               const u16* __restrict__ projwb,
                                               const float* __restrict__ proj_b,
                                               float* __restrict__ x1) {
  __shared__ __align__(16) u16 syb[64 * 104];
  __shared__ __align__(16) u16 sq [64 * 104];
  __shared__ __align__(16) u16 sk [64 * 104];
  __shared__ __align__(16) u16 svT[96 * 72];
  __shared__ __align__(16) u16 sp [4 * 16 * 72];
  const int tid  = threadIdx.x;
  const int wave = tid >> 6;
  const int lane = tid & 63;
  const int l16  = lane & 15;
  const int quad = lane >> 4;
  const int win  = blockIdx.x;
  const int t0   = wave * 16;
  const int bb = win >> 6, wl = win & 63;
  const int hbase = (wl >> 3) * WSZ, wbase = (wl & 7) * WSZ;

  // ---- LN1 head: 4 threads per token; gather from x with inverse global roll ----
  {
    const int t = tid >> 2, s = tid & 3;
    if (t < NT) {
      int hp = hbase + t / WSZ, wp = wbase + t % WSZ;
      int h = hp + SSH; if (h >= NHH) h -= NHH;
      int w = wp + SSH; if (w >= NWW) w -= NWW;
      const float* xp = x + ((size_t)bb * NL + (size_t)h * NWW + w) * NC;
      float4 v[6];
      float sum = 0.f;
      #pragma unroll
      for (int k = 0; k < 6; ++k) {
        v[k] = *reinterpret_cast<const float4*>(xp + s * 4 + k * 16);
        sum += v[k].x + v[k].y + v[k].z + v[k].w;
      }
      sum += __shfl_xor(sum, 1); sum += __shfl_xor(sum, 2);
      float mean = sum * (1.f / 96.f);
      float ssq = 0.f;
      #pragma unroll
      for (int k = 0; k < 6; ++k) {
        float d0 = v[k].x - mean, d1 = v[k].y - mean;
        float d2 = v[k].z - mean, d3 = v[k].w - mean;
        ssq += d0 * d0 + d1 * d1 + d2 * d2 + d3 * d3;
      }
      ssq += __shfl_xor(ssq, 1); ssq += __shfl_xor(ssq, 2);
      float rstd = rsqrtf(ssq * (1.f / 96.f) + 1e-5f);
      #pragma unroll
      for (int k = 0; k < 6; ++k) {
        int c = s * 4 + k * 16;
        const float4 g4 = *reinterpret_cast<const float4*>(n1g + c);
        const float4 b4 = *reinterpret_cast<const float4*>(n1b + c);
        syb[t * 104 + c + 0] = f2us((v[k].x - mean) * rstd * g4.x + b4.x);
        syb[t * 104 + c + 1] = f2us((v[k].y - mean) * rstd * g4.y + b4.y);
        syb[t * 104 + c + 2] = f2us((v[k].z - mean) * rstd * g4.z + b4.z);
        syb[t * 104 + c + 3] = f2us((v[k].w - mean) * rstd * g4.w + b4.w);
      }
    } else {
      #pragma unroll
      for (int k = 0; k < 6; ++k) {
        int c = s * 4 + k * 16;
        syb[t * 104 + c + 0] = 0; syb[t * 104 + c + 1] = 0;
        syb[t * 104 + c + 2] = 0; syb[t * 104 + c + 3] = 0;
      }
    }
  }
  __syncthreads();

  // ---- QKV: M=64, N=288 (18 tiles), K=96 (3 steps); depth-4 B-frag ring ----
  {
    short8 afr[3];
    #pragma unroll
    for (int ks = 0; ks < 3; ++ks)
      afr[ks] = *reinterpret_cast<const short8*>(&syb[(t0 + l16) * 104 + quad * 8 + ks * 32]);
    short8 rb[4][3];
    #pragma unroll
    for (int p = 0; p < 4; ++p)
      #pragma unroll
      for (int ks = 0; ks < 3; ++ks)
        rb[p][ks] = *reinterpret_cast<const short8*>(
            qkvwb + (size_t)(p * 16 + l16) * NC + quad * 8 + ks * 32);
    #pragma unroll
    for (int nt = 0; nt < 18; ++nt) {
      const int n0 = nt * 16;
      const float bias = qkv_b[n0 + l16];
      short8 b0 = rb[nt & 3][0], b1 = rb[nt & 3][1], b2 = rb[nt & 3][2];
      if (nt + 4 < 18) {
        #pragma unroll
        for (int ks = 0; ks < 3; ++ks)
          rb[nt & 3][ks] = *reinterpret_cast<const short8*>(
              qkvwb + (size_t)((nt + 4) * 16 + l16) * NC + quad * 8 + ks * 32);
      }
      f32x4 acc = {0.f, 0.f, 0.f, 0.f};
      acc = __builtin_amdgcn_mfma_f32_16x16x32_bf16(afr[0], b0, acc, 0, 0, 0);
      acc = __builtin_amdgcn_mfma_f32_16x16x32_bf16(afr[1], b1, acc, 0, 0, 0);
      acc = __builtin_amdgcn_mfma_f32_16x16x32_bf16(afr[2], b2, acc, 0, 0, 0);
      const int part = nt / 6;                 // 0=q 1=k 2=v
      const int oc = n0 - part * 96 + l16;
      if (part < 2) {
        u16* dst = (part == 0) ? sq : sk;
        #pragma unroll
        for (int r = 0; r < 4; ++r)
          dst[(t0 + quad * 4 + r) * 104 + oc] = f2us(acc[r] + bias);
      } else {
        #pragma unroll
        for (int r = 0; r < 4; ++r)
          svT[oc * 72 + (t0 + quad * 4 + r)] = f2us(acc[r] + bias);
      }
    }
  }
  __syncthreads();

  // ---- per head: scores -> in-register softmax -> PV (all wave-private) ----
  u16* spw = sp + wave * 16 * 72;
  const float sscale = 0.17677669529663687f;
  for (int h = 0; h < 3; ++h) {
    const int d0 = h * HDIM;
    short8 qf = *reinterpret_cast<const short8*>(&sq[(t0 + l16) * 104 + d0 + quad * 8]);
    f32x4 s[4];
    #pragma unroll
    for (int nt = 0; nt < 4; ++nt) {
      short8 kf = *reinterpret_cast<const short8*>(&sk[(nt * 16 + l16) * 104 + d0 + quad * 8]);
      f32x4 a = {0.f, 0.f, 0.f, 0.f};
      s[nt] = __builtin_amdgcn_mfma_f32_16x16x32_bf16(qf, kf, a, 0, 0, 0);
    }
    #pragma unroll
    for (int nt = 0; nt < 4; ++nt)
      #pragma unroll
      for (int r = 0; r < 4; ++r) s[nt][r] *= sscale;
    if (l16 >= 1) {                       // key col 48+l16 >= 49 -> mask
      #pragma unroll
      for (int r = 0; r < 4; ++r) s[3][r] = -1e30f;
    }
    #pragma unroll
    for (int r = 0; r < 4; ++r) {
      float m = fmaxf(fmaxf(s[0][r], s[1][r]), fmaxf(s[2][r], s[3][r]));
      #pragma unroll
      for (int off = 8; off > 0; off >>= 1) m = fmaxf(m, __shfl_xor(m, off, 16));
      float e0 = __expf(s[0][r] - m), e1 = __expf(s[1][r] - m);
      float e2 = __expf(s[2][r] - m), e3 = __expf(s[3][r] - m);
      float sum = e0 + e1 + e2 + e3;
      #pragma unroll
      for (int off = 8; off > 0; off >>= 1) sum += __shfl_xor(sum, off, 16);
      float inv = 1.f / sum;
      const int row = quad * 4 + r;
      spw[row * 72 +      l16] = f2us(e0 * inv);
      spw[row * 72 + 16 + l16] = f2us(e1 * inv);
      spw[row * 72 + 32 + l16] = f2us(e2 * inv);
      spw[row * 72 + 48 + l16] = f2us(e3 * inv);
    }
    short8 pa[2];
    pa[0] = *reinterpret_cast<const short8*>(&spw[l16 * 72 + quad * 8]);
    pa[1] = *reinterpret_cast<const short8*>(&spw[l16 * 72 + 32 + quad * 8]);
    #pragma unroll
    for (int nt = 0; nt < 2; ++nt) {
      const int c0 = d0 + nt * 16;
      f32x4 acc = {0.f, 0.f, 0.f, 0.f};
      #pragma unroll
      for (int ks = 0; ks < 2; ++ks) {
        short8 vb = *reinterpret_cast<const short8*>(&svT[(c0 + l16) * 72 + ks * 32 + quad * 8]);
        acc = __builtin_amdgcn_mfma_f32_16x16x32_bf16(pa[ks], vb, acc, 0, 0, 0);
      }
      #pragma unroll
      for (int r = 0; r < 4; ++r)
        syb[(t0 + quad * 4 + r) * 104 + c0 + l16] = f2us(acc[r]);
    }
  }

  // ---- proj: N=96 (6 tiles), K=96 (3 steps); prefetched residuals + depth-2 B ring ----
  {
    short8 aa[3];
    #pragma unroll
    for (int ks = 0; ks < 3; ++ks)
      aa[ks] = *reinterpret_cast<const short8*>(&syb[(t0 + l16) * 104 + quad * 8 + ks * 32]);

    size_t tokr[4]; bool tval[4];
    #pragma unroll
    for (int r = 0; r < 4; ++r) {
      const int t = t0 + quad * 4 + r;
      tval[r] = (t < NT);
      int rr = t / WSZ + SSH; if (rr >= WSZ) rr -= WSZ;
      int qq = t % WSZ + SSH; if (qq >= WSZ) qq -= WSZ;
      tokr[r] = (size_t)bb * NL + (size_t)(hbase + rr) * NWW + (wbase + qq);
    }
    float xv[6][4];
    #pragma unroll
    for (int nt = 0; nt < 6; ++nt)
      #pragma unroll
      for (int r = 0; r < 4; ++r)
        xv[nt][r] = tval[r] ? x[tokr[r] * NC + nt * 16 + l16] : 0.f;

    short8 pbr[2][3];
    #pragma unroll
    for (int ks = 0; ks < 3; ++ks)
      pbr[0][ks] = *reinterpret_cast<const short8*>(
          projwb + (size_t)l16 * NC + quad * 8 + ks * 32);
    #pragma unroll
    for (int nt = 0; nt < 6; ++nt) {
      const int n0 = nt * 16;
      const float pb = proj_b[n0 + l16];
      short8 b0 = pbr[nt & 1][0], b1 = pbr[nt & 1][1], b2 = pbr[nt & 1][2];
      if (nt + 1 < 6) {
        #pragma unroll
        for (int ks = 0; ks < 3; ++ks)
          pbr[(nt + 1) & 1][ks] = *reinterpret_cast<const short8*>(
              projwb + (size_t)((nt + 1) * 16 + l16) * NC + quad * 8 + ks * 32);
      }
      f32x4 acc = {0.f, 0.f, 0.f, 0.f};
      acc = __builtin_amdgcn_mfma_f32_16x16x32_bf16(aa[0], b0, acc, 0, 0, 0);
      acc = __builtin_amdgcn_mfma_f32_16x16x32_bf16(aa[1], b1, acc, 0, 0, 0);
      acc = __builtin_amdgcn_mfma_f32_16x16x32_bf16(aa[2], b2, acc, 0, 0, 0);
      #pragma unroll
      for (int r = 0; r < 4; ++r) {
        if (tval[r])
          x1[tokr[r] * NC + n0 + l16] = xv[nt][r] + acc[r] + pb;
      }
    }
  }
}

// ---------------- K4: double-LN + TM-FFN via MFMA; 32 tokens/block, 8 waves (512 thr) ----------------
// r9 structure + softplus literals (stride-776 lit, two u16 stores — conflict-free b128 reads)
// + szb/claT union + depth-8 maskb ring + epilogue/B-frag prefetch.
// LDS: lit 32x776 (49,664 B) + union(szb 32x104 / claT 32x136) (8,704 B) = 58,368 B -> 2 blocks/CU.
__global__ __launch_bounds__(512) void k4_ffn(const float* __restrict__ x1,
                                              const float* __restrict__ g2,
                                              const float* __restrict__ b2,
                                              const float* __restrict__ gf,
                                              const float* __restrict__ bf,
                                              const u16* __restrict__ pinwb,
                                              const float* __restrict__ pin_b,
                                              const u16* __restrict__ maskb,
                                              const u16* __restrict__ tmoT,
                                              const float* __restrict__ gate,
                                              float* __restrict__ out) {
  __shared__ __align__(16) u16 lit[32 * 776];   // bf16 log-literals [t][j]
  __shared__ __align__(16) u16 su[32 * 136];    // union: szb (32x104, dies early) / claT (32x136)
  u16* szb  = su;
  u16* claT = su;
  const int tid  = threadIdx.x;
  const int wave = tid >> 6;
  const int lane = tid & 63;
  const int l16  = lane & 15;
  const int quad = lane >> 4;
  const size_t tok0 = (size_t)blockIdx.x * 32;

  // ---- LN(LN(x1)) head: 16 lanes per token, 6 channels each (float2 x 3) ----
  {
    const int t = tid >> 4, s = tid & 15;
    const float* xp = x1 + (tok0 + t) * NC;
    float2 v[3];
    float sum = 0.f;
    #pragma unroll
    for (int k = 0; k < 3; ++k) {
      const int c = s * 2 + k * 32;
      v[k] = *reinterpret_cast<const float2*>(xp + c);
      sum += v[k].x + v[k].y;
    }
    #pragma unroll
    for (int off = 8; off > 0; off >>= 1) sum += __shfl_xor(sum, off, 16);
    const float mean = sum * (1.f / 96.f);
    float ssq = 0.f;
    #pragma unroll
    for (int k = 0; k < 3; ++k) {
      float d0 = v[k].x - mean, d1 = v[k].y - mean;
      ssq += d0 * d0 + d1 * d1;
    }
    #pragma unroll
    for (int off = 8; off > 0; off >>= 1) ssq += __shfl_xor(ssq, off, 16);
    const float rstd = rsqrtf(ssq * (1.f / 96.f) + 1e-5f);
    float tv[6];
    float sum2 = 0.f;
    #pragma unroll
    for (int k = 0; k < 3; ++k) {
      const int c = s * 2 + k * 32;
      const float2 gg = *reinterpret_cast<const float2*>(g2 + c);
      const float2 bb = *reinterpret_cast<const float2*>(b2 + c);
      tv[2 * k]     = (v[k].x - mean) * rstd * gg.x + bb.x;
      tv[2 * k + 1] = (v[k].y - mean) * rstd * gg.y + bb.y;
      sum2 += tv[2 * k] + tv[2 * k + 1];
    }
    #pragma unroll
    for (int off = 8; off > 0; off >>= 1) sum2 += __shfl_xor(sum2, off, 16);
    const float mean2 = sum2 * (1.f / 96.f);
    float ssq2 = 0.f;
    #pragma unroll
    for (int k = 0; k < 3; ++k) {
      float d0 = tv[2 * k] - mean2, d1 = tv[2 * k + 1] - mean2;
      ssq2 += d0 * d0 + d1 * d1;
    }
    #pragma unroll
    for (int off = 8; off > 0; off >>= 1) ssq2 += __shfl_xor(ssq2, off, 16);
    const float rstd2 = rsqrtf(ssq2 * (1.f / 96.f) + 1e-5f);
    #pragma unroll
    for (int k = 0; k < 3; ++k) {
      const int c = s * 2 + k * 32;
      const float2 gg = *reinterpret_cast<const float2*>(gf + c);
      const float2 bb = *reinterpret_cast<const float2*>(bf + c);
      u16 lo = f2us((tv[2 * k]     - mean2) * rstd2 * gg.x + bb.x);
      u16 hi = f2us((tv[2 * k + 1] - mean2) * rstd2 * gg.y + bb.y);
      *reinterpret_cast<u32*>(&szb[t * 104 + c]) = (u32)lo | ((u32)hi << 16);
    }
  }
  __syncthreads();   // B1: szb complete

  const float gv = sigmoidf_(gate[0]);

  // A-frags for both pin M-tiles (szb dies after these loads; claT reuses su after B2)
  short8 a_pin[2][3];
  #pragma unroll
  for (int mt = 0; mt < 2; ++mt)
    #pragma unroll
    for (int ks = 0; ks < 3; ++ks)
      a_pin[mt][ks] = *reinterpret_cast<const short8*>(
          &szb[(mt * 16 + l16) * 104 + quad * 8 + ks * 32]);

  // ---- pin gemm: wave w -> N-tiles [3w,3w+3); ALL 9 B-frags loaded up front; 2 MFMA per B-frag;
  //      softplus literals: log(sig(a)) = a - sp, log(1-sig(a)) = -sp ----
  {
    float pbias[3];
    #pragma unroll
    for (int i = 0; i < 3; ++i) pbias[i] = pin_b[(wave * 3 + i) * 16 + l16];
    short8 pb[3][3];
    #pragma unroll
    for (int i = 0; i < 3; ++i)
      #pragma unroll
      for (int ks = 0; ks < 3; ++ks)
        pb[i][ks] = *reinterpret_cast<const short8*>(
            pinwb + (size_t)((wave * 3 + i) * 16 + l16) * NC + quad * 8 + ks * 32);
    #pragma unroll
    for (int i = 0; i < 3; ++i) {
      f32x4 acc0 = {0.f, 0.f, 0.f, 0.f}, acc1 = {0.f, 0.f, 0.f, 0.f};
      acc0 = __builtin_amdgcn_mfma_f32_16x16x32_bf16(a_pin[0][0], pb[i][0], acc0, 0, 0, 0);
      acc1 = __builtin_amdgcn_mfma_f32_16x16x32_bf16(a_pin[1][0], pb[i][0], acc1, 0, 0, 0);
      acc0 = __builtin_amdgcn_mfma_f32_16x16x32_bf16(a_pin[0][1], pb[i][1], acc0, 0, 0, 0);
      acc1 = __builtin_amdgcn_mfma_f32_16x16x32_bf16(a_pin[1][1], pb[i][1], acc1, 0, 0, 0);
      acc0 = __builtin_amdgcn_mfma_f32_16x16x32_bf16(a_pin[0][2], pb[i][2], acc0, 0, 0, 0);
      acc1 = __builtin_amdgcn_mfma_f32_16x16x32_bf16(a_pin[1][2], pb[i][2], acc1, 0, 0, 0);
      const int o = (wave * 3 + i) * 16 + l16;
      const float pbv = pbias[i];
      #pragma unroll
      for (int r = 0; r < 4; ++r) {
        const float a0 = acc0[r] + pbv;
        const float sp0 = fmaxf(a0, 0.f) + __logf(1.f + __expf(-fabsf(a0)));
        const float a1 = acc1[r] + pbv;
        const float sp1 = fmaxf(a1, 0.f) + __logf(1.f + __expf(-fabsf(a1)));
        const int ta = quad * 4 + r, tb = 16 + quad * 4 + r;
        lit[ta * 776 + o]       = f2us(fmaxf(a0 - sp0, LOG_EPS));
        lit[ta * 776 + 384 + o] = f2us(fmaxf(-sp0, LOG_EPS));
        lit[tb * 776 + o]       = f2us(fmaxf(a1 - sp1, LOG_EPS));
        lit[tb * 776 + 384 + o] = f2us(fmaxf(-sp1, LOG_EPS));
      }
    }
  }
  __syncthreads();   // B2: lit complete (also fences a_pin/szb reads vs claT writes)

  // prefetch epilogue residuals (hidden behind the clause gemm)
  float xr[2][4];
  if (wave < 6) {
    const int c = wave * 16 + l16;
    #pragma unroll
    for (int r = 0; r < 4; ++r) {
      xr[0][r] = x1[(tok0 + quad * 4 + r) * NC + c];
      xr[1][r] = x1[(tok0 + 16 + quad * 4 + r) * NC + c];
    }
  }

  // ---- clause gemm: wave w -> clause tile w; depth-8 B ring; 2 MFMA per B-frag ----
  {
    const int ct = wave;
    const u16* bp0 = maskb + (size_t)(ct * 16 + l16) * NLIT + quad * 8;
    short8 rb0[8];
    #pragma unroll
    for (int p = 0; p < 8; ++p)
      rb0[p] = *reinterpret_cast<const short8*>(bp0 + p * 32);
    f32x4 c00 = {0.f, 0.f, 0.f, 0.f}, c10 = {0.f, 0.f, 0.f, 0.f};
    #pragma unroll
    for (int ks = 0; ks < 24; ++ks) {
      const int k0 = ks * 32 + quad * 8;
      short8 a0 = *reinterpret_cast<const short8*>(&lit[l16 * 776 + k0]);
      short8 a1 = *reinterpret_cast<const short8*>(&lit[(16 + l16) * 776 + k0]);
      short8 b0 = rb0[ks & 7];
      if (ks + 8 < 24)
        rb0[ks & 7] = *reinterpret_cast<const short8*>(bp0 + (ks + 8) * 32);
      c00 = __builtin_amdgcn_mfma_f32_16x16x32_bf16(a0, b0, c00, 0, 0, 0);
      c10 = __builtin_amdgcn_mfma_f32_16x16x32_bf16(a1, b0, c10, 0, 0, 0);
    }
    #pragma unroll
    for (int r = 0; r < 4; ++r) {
      const int ta = quad * 4 + r, tb = 16 + quad * 4 + r;
      claT[ta * 136 + ct * 16 + l16] = f2us(__expf(c00[r]));
      claT[tb * 136 + ct * 16 + l16] = f2us(__expf(c10[r]));
    }
  }
  __syncthreads();   // B3: claT complete

  // ---- logits = cla @ tm_out; 6 N-tiles over waves 0-5; fused blend epilogue ----
  if (wave < 6) {
    const int nt = wave;
    short8 btm[4];
    #pragma unroll
    for (int ks = 0; ks < 4; ++ks)
      btm[ks] = *reinterpret_cast<const short8*>(
          tmoT + (size_t)(nt * 16 + l16) * NCL_ + ks * 32 + quad * 8);
    f32x4 acc0 = {0.f, 0.f, 0.f, 0.f}, acc1 = {0.f, 0.f, 0.f, 0.f};
    #pragma unroll
    for (int ks = 0; ks < 4; ++ks) {
      const int k0 = ks * 32 + quad * 8;
      short8 a0 = *reinterpret_cast<const short8*>(&claT[l16 * 136 + k0]);
      short8 a1 = *reinterpret_cast<const short8*>(&claT[(16 + l16) * 136 + k0]);
      acc0 = __builtin_amdgcn_mfma_f32_16x16x32_bf16(a0, btm[ks], acc0, 0, 0, 0);
      acc1 = __builtin_amdgcn_mfma_f32_16x16x32_bf16(a1, btm[ks], acc1, 0, 0, 0);
    }
    const int c = nt * 16 + l16;
    #pragma unroll
    for (int r = 0; r < 4; ++r) {
      const int ta = quad * 4 + r, tb = 16 + quad * 4 + r;
      float lg0 = acc0[r], lg1 = acc1[r];
      out[(tok0 + ta) * NC + c] = xr[0][r] + gv * lg0 + (1.f - gv) * sigmoidf_(lg0);
      out[(tok0 + tb) * NC + c] = xr[1][r] + gv * lg1 + (1.f - gv) * sigmoidf_(lg1);
    }
  }
}

extern "C" void kernel_launch(void* const* d_in, const int* in_sizes, int n_in,
                              void* d_out, int out_size, void* d_ws, size_t ws_size,
                              hipStream_t stream) {
  (void)in_sizes; (void)n_in; (void)out_size; (void)ws_size;
  const float* x      = (const float*)d_in[0];
  const float* n1g    = (const float*)d_in[1];
  const float* n1b    = (const float*)d_in[2];
  const float* qkv_w  = (const float*)d_in[3];
  const float* qkv_b  = (const float*)d_in[4];
  const float* proj_w = (const float*)d_in[5];
  const float* proj_b = (const float*)d_in[6];
  const float* n2g    = (const float*)d_in[7];
  const float* n2b    = (const float*)d_in[8];
  const float* fng    = (const float*)d_in[9];
  const float* fnb    = (const float*)d_in[10];
  const float* pin_w  = (const float*)d_in[11];
  const float* pin_b  = (const float*)d_in[12];
  const float* tm_inc = (const float*)d_in[13];
  const float* tm_out = (const float*)d_in[14];
  const float* gate   = (const float*)d_in[15];

  float* x1 = (float*)d_ws;                         // NTOK*96 f32
  u16* maskb = (u16*)(x1 + (size_t)NTOK * NC);      // 128*768 bf16
  u16* pinwb = maskb + NCL_ * NLIT;                 // 384*96 bf16
  u16* tmoT  = pinwb + HID_ * NC;                   // 96*128 bf16
  u16* qkvwb = tmoT + NC * NCL_;                    // 288*96 bf16
  u16* projwb= qkvwb + 3 * NC * NC;                 // 96*96 bf16

  hipLaunchKernelGGL(k0_prep, dim3(384), dim3(256), 0, stream,
                     tm_inc, pin_w, tm_out, qkv_w, proj_w, maskb, pinwb, tmoT, qkvwb, projwb);
  hipLaunchKernelGGL(k2_attn, dim3(NWIN), dim3(256), 0, stream,
                     x, n1g, n1b, qkvwb, qkv_b, projwb, proj_b, x1);
  hipLaunchKernelGGL(k4_ffn, dim3(NTOK / 32), dim3(512), 0, stream,
                     x1, n2g, n2b, fng, fnb, pinwb, pin_b, maskb, tmoT, gate, (float*)d_out);
}

// Round 13
// 194.018 us; speedup vs baseline: 1.2157x; 1.0136x over previous
//
#include <hip/hip_runtime.h>

// ---- problem constants (B,H0,W0,C)=(16,56,56,96), NH=3, WS=7, SS=3, HID=384, NCL=128 ----
#define NB 16
#define NHH 56
#define NWW 56
#define NC 96
#define NL (NHH*NWW)          // 3136
#define NTOK (NB*NL)          // 50176
#define WSZ 7
#define NT 49                 // tokens per window
#define SSH 3
#define NWIN 1024             // 16 * 8 * 8
#define HDIM 32
#define HID_ 384
#define NCL_ 128
#define NLIT 768
#define EPS_ 1e-6f
#define LOG_EPS -13.815510558f

typedef unsigned short u16;
typedef unsigned int   u32;
typedef __attribute__((ext_vector_type(8))) short short8;   // 8 bf16 (4 VGPRs)
typedef __attribute__((ext_vector_type(4))) float f32x4;    // MFMA C/D

__device__ __forceinline__ float us2f(u16 u) {
  union { u32 u; float f; } x; x.u = ((u32)u) << 16; return x.f;
}
__device__ __forceinline__ u16 f2us(float f) {   // RNE float->bf16
  union { float f; u32 u; } x; x.f = f;
  u32 lsb = (x.u >> 16) & 1u;
  return (u16)((x.u + 0x7fffu + lsb) >> 16);
}
__device__ __forceinline__ float sigmoidf_(float x) { return 1.f / (1.f + __expf(-x)); }

// ---------------- K0: build bf16 constants ----------------
__global__ __launch_bounds__(256) void k0_prep(const float* __restrict__ tm_inc,
                                               const float* __restrict__ pin_w,
                                               const float* __restrict__ tm_out,
                                               const float* __restrict__ qkv_w,
                                               const float* __restrict__ proj_w,
                                               u16* __restrict__ maskb,
                                               u16* __restrict__ pinwb,
                                               u16* __restrict__ tmoT,
                                               u16* __restrict__ qkvwb,
                                               u16* __restrict__ projwb) {
  int idx = blockIdx.x * 256 + threadIdx.x;
  if (idx < NCL_ * NLIT)
    maskb[idx] = (tm_inc[idx] > 0.f) ? (u16)0x3F80 : (u16)0;
  if (idx < HID_ * NC)
    pinwb[idx] = f2us(pin_w[idx]);
  if (idx < NC * NCL_) {
    int c = idx / NCL_, k = idx - c * NCL_;
    tmoT[idx] = f2us(tm_out[(size_t)k * NC + c]);
  }
  if (idx < 3 * NC * NC)
    qkvwb[idx] = f2us(qkv_w[idx]);
  if (idx < NC * NC)
    projwb[idx] = f2us(proj_w[idx]);
}

// ---------------- K2: LN1 + window gather + MFMA attention + proj + residual scatter ----------------
// One block = one window. 4 waves; wave w owns query rows 16w..16w+15.
// syb triple-duty: LN1'd y -> q (QKV phase, wave-own rows) -> attn-out (PV, wave-own rows).
// LDS: syb 13,312 + sk 13,312 + svT 13,824 + sp 9,216 = 49,664 B -> 3 blocks/CU (12 waves, 37.5%).
__global__ __launch_bounds__(256) void k2_attn(const float* __restrict__ x,
                                               const float* __restrict__ n1g,
                                               const float* __restrict__ n1b,
                                               const u16* __restrict__ qkvwb,
                                               const float* __restrict__ qkv_b,
                                               const u16* __restrict__ projwb,
                                               const float* __restrict__ proj_b,
                                               float* __restrict__ x1) {
  __shared__ __align__(16) u16 syb[64 * 104];
  __shared__ __align__(16) u16 sk [64 * 104];
  __shared__ __align__(16) u16 svT[96 * 72];
  __shared__ __align__(16) u16 sp [4 * 16 * 72];
  const int tid  = threadIdx.x;
  const int wave = tid >> 6;
  const int lane = tid & 63;
  const int l16  = lane & 15;
  const int quad = lane >> 4;
  const int win  = blockIdx.x;
  const int t0   = wave * 16;
  const int bb = win >> 6, wl = win & 63;
  const int hbase = (wl >> 3) * WSZ, wbase = (wl & 7) * WSZ;

  // ---- LN1 head: 4 threads per token; gather from x with inverse global roll ----
  {
    const int t = tid >> 2, s = tid & 3;
    if (t < NT) {
      int hp = hbase + t / WSZ, wp = wbase + t % WSZ;
      int h = hp + SSH; if (h >= NHH) h -= NHH;
      int w = wp + SSH; if (w >= NWW) w -= NWW;
      const float* xp = x + ((size_t)bb * NL + (size_t)h * NWW + w) * NC;
      float4 v[6];
      float sum = 0.f;
      #pragma unroll
      for (int k = 0; k < 6; ++k) {
        v[k] = *reinterpret_cast<const float4*>(xp + s * 4 + k * 16);
        sum += v[k].x + v[k].y + v[k].z + v[k].w;
      }
      sum += __shfl_xor(sum, 1); sum += __shfl_xor(sum, 2);
      float mean = sum * (1.f / 96.f);
      float ssq = 0.f;
      #pragma unroll
      for (int k = 0; k < 6; ++k) {
        float d0 = v[k].x - mean, d1 = v[k].y - mean;
        float d2 = v[k].z - mean, d3 = v[k].w - mean;
        ssq += d0 * d0 + d1 * d1 + d2 * d2 + d3 * d3;
      }
      ssq += __shfl_xor(ssq, 1); ssq += __shfl_xor(ssq, 2);
      float rstd = rsqrtf(ssq * (1.f / 96.f) + 1e-5f);
      #pragma unroll
      for (int k = 0; k < 6; ++k) {
        int c = s * 4 + k * 16;
        const float4 g4 = *reinterpret_cast<const float4*>(n1g + c);
        const float4 b4 = *reinterpret_cast<const float4*>(n1b + c);
        syb[t * 104 + c + 0] = f2us((v[k].x - mean) * rstd * g4.x + b4.x);
        syb[t * 104 + c + 1] = f2us((v[k].y - mean) * rstd * g4.y + b4.y);
        syb[t * 104 + c + 2] = f2us((v[k].z - mean) * rstd * g4.z + b4.z);
        syb[t * 104 + c + 3] = f2us((v[k].w - mean) * rstd * g4.w + b4.w);
      }
    } else {
      #pragma unroll
      for (int k = 0; k < 6; ++k) {
        int c = s * 4 + k * 16;
        syb[t * 104 + c + 0] = 0; syb[t * 104 + c + 1] = 0;
        syb[t * 104 + c + 2] = 0; syb[t * 104 + c + 3] = 0;
      }
    }
  }
  __syncthreads();

  // ---- QKV: M=64, N=288 (18 tiles), K=96 (3 steps); depth-4 B-frag ring.
  //      q is written back into syb (wave-own rows; y in those rows is dead after afr loads,
  //      and same-wave DS ordering guarantees the afr reads complete first). ----
  {
    short8 afr[3];
    #pragma unroll
    for (int ks = 0; ks < 3; ++ks)
      afr[ks] = *reinterpret_cast<const short8*>(&syb[(t0 + l16) * 104 + quad * 8 + ks * 32]);
    short8 rb[4][3];
    #pragma unroll
    for (int p = 0; p < 4; ++p)
      #pragma unroll
      for (int ks = 0; ks < 3; ++ks)
        rb[p][ks] = *reinterpret_cast<const short8*>(
            qkvwb + (size_t)(p * 16 + l16) * NC + quad * 8 + ks * 32);
    #pragma unroll
    for (int nt = 0; nt < 18; ++nt) {
      const int n0 = nt * 16;
      const float bias = qkv_b[n0 + l16];
      short8 b0 = rb[nt & 3][0], b1 = rb[nt & 3][1], b2 = rb[nt & 3][2];
      if (nt + 4 < 18) {
        #pragma unroll
        for (int ks = 0; ks < 3; ++ks)
          rb[nt & 3][ks] = *reinterpret_cast<const short8*>(
              qkvwb + (size_t)((nt + 4) * 16 + l16) * NC + quad * 8 + ks * 32);
      }
      f32x4 acc = {0.f, 0.f, 0.f, 0.f};
      acc = __builtin_amdgcn_mfma_f32_16x16x32_bf16(afr[0], b0, acc, 0, 0, 0);
      acc = __builtin_amdgcn_mfma_f32_16x16x32_bf16(afr[1], b1, acc, 0, 0, 0);
      acc = __builtin_amdgcn_mfma_f32_16x16x32_bf16(afr[2], b2, acc, 0, 0, 0);
      const int part = nt / 6;                 // 0=q 1=k 2=v
      const int oc = n0 - part * 96 + l16;
      if (part < 2) {
        u16* dst = (part == 0) ? syb : sk;     // q overwrites y in wave-own rows
        #pragma unroll
        for (int r = 0; r < 4; ++r)
          dst[(t0 + quad * 4 + r) * 104 + oc] = f2us(acc[r] + bias);
      } else {
        #pragma unroll
        for (int r = 0; r < 4; ++r)
          svT[oc * 72 + (t0 + quad * 4 + r)] = f2us(acc[r] + bias);
      }
    }
  }
  __syncthreads();

  // ---- per head: scores -> in-register softmax -> PV (all wave-private).
  //      qf reads q from syb (own rows, cols d0..d0+31) BEFORE attn-out overwrites those cols. ----
  u16* spw = sp + wave * 16 * 72;
  const float sscale = 0.17677669529663687f;
  for (int h = 0; h < 3; ++h) {
    const int d0 = h * HDIM;
    short8 qf = *reinterpret_cast<const short8*>(&syb[(t0 + l16) * 104 + d0 + quad * 8]);
    f32x4 s[4];
    #pragma unroll
    for (int nt = 0; nt < 4; ++nt) {
      short8 kf = *reinterpret_cast<const short8*>(&sk[(nt * 16 + l16) * 104 + d0 + quad * 8]);
      f32x4 a = {0.f, 0.f, 0.f, 0.f};
      s[nt] = __builtin_amdgcn_mfma_f32_16x16x32_bf16(qf, kf, a, 0, 0, 0);
    }
    #pragma unroll
    for (int nt = 0; nt < 4; ++nt)
      #pragma unroll
      for (int r = 0; r < 4; ++r) s[nt][r] *= sscale;
    if (l16 >= 1) {                       // key col 48+l16 >= 49 -> mask
      #pragma unroll
      for (int r = 0; r < 4; ++r) s[3][r] = -1e30f;
    }
    #pragma unroll
    for (int r = 0; r < 4; ++r) {
      float m = fmaxf(fmaxf(s[0][r], s[1][r]), fmaxf(s[2][r], s[3][r]));
      #pragma unroll
      for (int off = 8; off > 0; off >>= 1) m = fmaxf(m, __shfl_xor(m, off, 16));
      float e0 = __expf(s[0][r] - m), e1 = __expf(s[1][r] - m);
      float e2 = __expf(s[2][r] - m), e3 = __expf(s[3][r] - m);
      float sum = e0 + e1 + e2 + e3;
      #pragma unroll
      for (int off = 8; off > 0; off >>= 1) sum += __shfl_xor(sum, off, 16);
      float inv = 1.f / sum;
      const int row = quad * 4 + r;
      spw[row * 72 +      l16] = f2us(e0 * inv);
      spw[row * 72 + 16 + l16] = f2us(e1 * inv);
      spw[row * 72 + 32 + l16] = f2us(e2 * inv);
      spw[row * 72 + 48 + l16] = f2us(e3 * inv);
    }
    short8 pa[2];
    pa[0] = *reinterpret_cast<const short8*>(&spw[l16 * 72 + quad * 8]);
    pa[1] = *reinterpret_cast<const short8*>(&spw[l16 * 72 + 32 + quad * 8]);
    #pragma unroll
    for (int nt = 0; nt < 2; ++nt) {
      const int c0 = d0 + nt * 16;
      f32x4 acc = {0.f, 0.f, 0.f, 0.f};
      #pragma unroll
      for (int ks = 0; ks < 2; ++ks) {
        short8 vb = *reinterpret_cast<const short8*>(&svT[(c0 + l16) * 72 + ks * 32 + quad * 8]);
        acc = __builtin_amdgcn_mfma_f32_16x16x32_bf16(pa[ks], vb, acc, 0, 0, 0);
      }
      #pragma unroll
      for (int r = 0; r < 4; ++r)
        syb[(t0 + quad * 4 + r) * 104 + c0 + l16] = f2us(acc[r]);
    }
  }

  // ---- proj: N=96 (6 tiles), K=96 (3 steps); prefetched residuals + depth-2 B ring ----
  {
    short8 aa[3];
    #pragma unroll
    for (int ks = 0; ks < 3; ++ks)
      aa[ks] = *reinterpret_cast<const short8*>(&syb[(t0 + l16) * 104 + quad * 8 + ks * 32]);

    size_t tokr[4]; bool tval[4];
    #pragma unroll
    for (int r = 0; r < 4; ++r) {
      const int t = t0 + quad * 4 + r;
      tval[r] = (t < NT);
      int rr = t / WSZ + SSH; if (rr >= WSZ) rr -= WSZ;
      int qq = t % WSZ + SSH; if (qq >= WSZ) qq -= WSZ;
      tokr[r] = (size_t)bb * NL + (size_t)(hbase + rr) * NWW + (wbase + qq);
    }
    float xv[6][4];
    #pragma unroll
    for (int nt = 0; nt < 6; ++nt)
      #pragma unroll
      for (int r = 0; r < 4; ++r)
        xv[nt][r] = tval[r] ? x[tokr[r] * NC + nt * 16 + l16] : 0.f;

    short8 pbr[2][3];
    #pragma unroll
    for (int ks = 0; ks < 3; ++ks)
      pbr[0][ks] = *reinterpret_cast<const short8*>(
          projwb + (size_t)l16 * NC + quad * 8 + ks * 32);
    #pragma unroll
    for (int nt = 0; nt < 6; ++nt) {
      const int n0 = nt * 16;
      const float pb = proj_b[n0 + l16];
      short8 b0 = pbr[nt & 1][0], b1 = pbr[nt & 1][1], b2 = pbr[nt & 1][2];
      if (nt + 1 < 6) {
        #pragma unroll
        for (int ks = 0; ks < 3; ++ks)
          pbr[(nt + 1) & 1][ks] = *reinterpret_cast<const short8*>(
              projwb + (size_t)((nt + 1) * 16 + l16) * NC + quad * 8 + ks * 32);
      }
      f32x4 acc = {0.f, 0.f, 0.f, 0.f};
      acc = __builtin_amdgcn_mfma_f32_16x16x32_bf16(aa[0], b0, acc, 0, 0, 0);
      acc = __builtin_amdgcn_mfma_f32_16x16x32_bf16(aa[1], b1, acc, 0, 0, 0);
      acc = __builtin_amdgcn_mfma_f32_16x16x32_bf16(aa[2], b2, acc, 0, 0, 0);
      #pragma unroll
      for (int r = 0; r < 4; ++r) {
        if (tval[r])
          x1[tokr[r] * NC + n0 + l16] = xv[nt][r] + acc[r] + pb;
      }
    }
  }
}

// ---------------- K4: double-LN + TM-FFN via MFMA; 32 tokens/block, 8 waves (512 thr) ----------------
// (unchanged from round 12: softplus literals, stride-776 lit, szb/claT union,
//  depth-8 maskb ring, epilogue/B-frag prefetch. LDS 58,368 B -> 2 blocks/CU.)
__global__ __launch_bounds__(512) void k4_ffn(const float* __restrict__ x1,
                                              const float* __restrict__ g2,
                                              const float* __restrict__ b2,
                                              const float* __restrict__ gf,
                                              const float* __restrict__ bf,
                                              const u16* __restrict__ pinwb,
                                              const float* __restrict__ pin_b,
                                              const u16* __restrict__ maskb,
                                              const u16* __restrict__ tmoT,
                                              const float* __restrict__ gate,
                                              float* __restrict__ out) {
  __shared__ __align__(16) u16 lit[32 * 776];   // bf16 log-literals [t][j]
  __shared__ __align__(16) u16 su[32 * 136];    // union: szb (32x104, dies early) / claT (32x136)
  u16* szb  = su;
  u16* claT = su;
  const int tid  = threadIdx.x;
  const int wave = tid >> 6;
  const int lane = tid & 63;
  const int l16  = lane & 15;
  const int quad = lane >> 4;
  const size_t tok0 = (size_t)blockIdx.x * 32;

  // ---- LN(LN(x1)) head: 16 lanes per token, 6 channels each (float2 x 3) ----
  {
    const int t = tid >> 4, s = tid & 15;
    const float* xp = x1 + (tok0 + t) * NC;
    float2 v[3];
    float sum = 0.f;
    #pragma unroll
    for (int k = 0; k < 3; ++k) {
      const int c = s * 2 + k * 32;
      v[k] = *reinterpret_cast<const float2*>(xp + c);
      sum += v[k].x + v[k].y;
    }
    #pragma unroll
    for (int off = 8; off > 0; off >>= 1) sum += __shfl_xor(sum, off, 16);
    const float mean = sum * (1.f / 96.f);
    float ssq = 0.f;
    #pragma unroll
    for (int k = 0; k < 3; ++k) {
      float d0 = v[k].x - mean, d1 = v[k].y - mean;
      ssq += d0 * d0 + d1 * d1;
    }
    #pragma unroll
    for (int off = 8; off > 0; off >>= 1) ssq += __shfl_xor(ssq, off, 16);
    const float rstd = rsqrtf(ssq * (1.f / 96.f) + 1e-5f);
    float tv[6];
    float sum2 = 0.f;
    #pragma unroll
    for (int k = 0; k < 3; ++k) {
      const int c = s * 2 + k * 32;
      const float2 gg = *reinterpret_cast<const float2*>(g2 + c);
      const float2 bb = *reinterpret_cast<const float2*>(b2 + c);
      tv[2 * k]     = (v[k].x - mean) * rstd * gg.x + bb.x;
      tv[2 * k + 1] = (v[k].y - mean) * rstd * gg.y + bb.y;
      sum2 += tv[2 * k] + tv[2 * k + 1];
    }
    #pragma unroll
    for (int off = 8; off > 0; off >>= 1) sum2 += __shfl_xor(sum2, off, 16);
    const float mean2 = sum2 * (1.f / 96.f);
    float ssq2 = 0.f;
    #pragma unroll
    for (int k = 0; k < 3; ++k) {
      float d0 = tv[2 * k] - mean2, d1 = tv[2 * k + 1] - mean2;
      ssq2 += d0 * d0 + d1 * d1;
    }
    #pragma unroll
    for (int off = 8; off > 0; off >>= 1) ssq2 += __shfl_xor(ssq2, off, 16);
    const float rstd2 = rsqrtf(ssq2 * (1.f / 96.f) + 1e-5f);
    #pragma unroll
    for (int k = 0; k < 3; ++k) {
      const int c = s * 2 + k * 32;
      const float2 gg = *reinterpret_cast<const float2*>(gf + c);
      const float2 bb = *reinterpret_cast<const float2*>(bf + c);
      u16 lo = f2us((tv[2 * k]     - mean2) * rstd2 * gg.x + bb.x);
      u16 hi = f2us((tv[2 * k + 1] - mean2) * rstd2 * gg.y + bb.y);
      *reinterpret_cast<u32*>(&szb[t * 104 + c]) = (u32)lo | ((u32)hi << 16);
    }
  }
  __syncthreads();   // B1: szb complete

  const float gv = sigmoidf_(gate[0]);

  // A-frags for both pin M-tiles (szb dies after these loads; claT reuses su after B2)
  short8 a_pin[2][3];
  #pragma unroll
  for (int mt = 0; mt < 2; ++mt)
    #pragma unroll
    for (int ks = 0; ks < 3; ++ks)
      a_pin[mt][ks] = *reinterpret_cast<const short8*>(
          &szb[(mt * 16 + l16) * 104 + quad * 8 + ks * 32]);

  // ---- pin gemm: wave w -> N-tiles [3w,3w+3); ALL 9 B-frags loaded up front; 2 MFMA per B-frag;
  //      softplus literals: log(sig(a)) = a - sp, log(1-sig(a)) = -sp ----
  {
    float pbias[3];
    #pragma unroll
    for (int i = 0; i < 3; ++i) pbias[i] = pin_b[(wave * 3 + i) * 16 + l16];
    short8 pb[3][3];
    #pragma unroll
    for (int i = 0; i < 3; ++i)
      #pragma unroll
      for (int ks = 0; ks < 3; ++ks)
        pb[i][ks] = *reinterpret_cast<const short8*>(
            pinwb + (size_t)((wave * 3 + i) * 16 + l16) * NC + quad * 8 + ks * 32);
    #pragma unroll
    for (int i = 0; i < 3; ++i) {
      f32x4 acc0 = {0.f, 0.f, 0.f, 0.f}, acc1 = {0.f, 0.f, 0.f, 0.f};
      acc0 = __builtin_amdgcn_mfma_f32_16x16x32_bf16(a_pin[0][0], pb[i][0], acc0, 0, 0, 0);
      acc1 = __builtin_amdgcn_mfma_f32_16x16x32_bf16(a_pin[1][0], pb[i][0], acc1, 0, 0, 0);
      acc0 = __builtin_amdgcn_mfma_f32_16x16x32_bf16(a_pin[0][1], pb[i][1], acc0, 0, 0, 0);
      acc1 = __builtin_amdgcn_mfma_f32_16x16x32_bf16(a_pin[1][1], pb[i][1], acc1, 0, 0, 0);
      acc0 = __builtin_amdgcn_mfma_f32_16x16x32_bf16(a_pin[0][2], pb[i][2], acc0, 0, 0, 0);
      acc1 = __builtin_amdgcn_mfma_f32_16x16x32_bf16(a_pin[1][2], pb[i][2], acc1, 0, 0, 0);
      const int o = (wave * 3 + i) * 16 + l16;
      const float pbv = pbias[i];
      #pragma unroll
      for (int r = 0; r < 4; ++r) {
        const float a0 = acc0[r] + pbv;
        const float sp0 = fmaxf(a0, 0.f) + __logf(1.f + __expf(-fabsf(a0)));
        const float a1 = acc1[r] + pbv;
        const float sp1 = fmaxf(a1, 0.f) + __logf(1.f + __expf(-fabsf(a1)));
        const int ta = quad * 4 + r, tb = 16 + quad * 4 + r;
        lit[ta * 776 + o]       = f2us(fmaxf(a0 - sp0, LOG_EPS));
        lit[ta * 776 + 384 + o] = f2us(fmaxf(-sp0, LOG_EPS));
        lit[tb * 776 + o]       = f2us(fmaxf(a1 - sp1, LOG_EPS));
        lit[tb * 776 + 384 + o] = f2us(fmaxf(-sp1, LOG_EPS));
      }
    }
  }
  __syncthreads();   // B2: lit complete (also fences a_pin/szb reads vs claT writes)

  // prefetch epilogue residuals (hidden behind the clause gemm)
  float xr[2][4];
  if (wave < 6) {
    const int c = wave * 16 + l16;
    #pragma unroll
    for (int r = 0; r < 4; ++r) {
      xr[0][r] = x1[(tok0 + quad * 4 + r) * NC + c];
      xr[1][r] = x1[(tok0 + 16 + quad * 4 + r) * NC + c];
    }
  }

  // ---- clause gemm: wave w -> clause tile w; depth-8 B ring; 2 MFMA per B-frag ----
  {
    const int ct = wave;
    const u16* bp0 = maskb + (size_t)(ct * 16 + l16) * NLIT + quad * 8;
    short8 rb0[8];
    #pragma unroll
    for (int p = 0; p < 8; ++p)
      rb0[p] = *reinterpret_cast<const short8*>(bp0 + p * 32);
    f32x4 c00 = {0.f, 0.f, 0.f, 0.f}, c10 = {0.f, 0.f, 0.f, 0.f};
    #pragma unroll
    for (int ks = 0; ks < 24; ++ks) {
      const int k0 = ks * 32 + quad * 8;
      short8 a0 = *reinterpret_cast<const short8*>(&lit[l16 * 776 + k0]);
      short8 a1 = *reinterpret_cast<const short8*>(&lit[(16 + l16) * 776 + k0]);
      short8 b0 = rb0[ks & 7];
      if (ks + 8 < 24)
        rb0[ks & 7] = *reinterpret_cast<const short8*>(bp0 + (ks + 8) * 32);
      c00 = __builtin_amdgcn_mfma_f32_16x16x32_bf16(a0, b0, c00, 0, 0, 0);
      c10 = __builtin_amdgcn_mfma_f32_16x16x32_bf16(a1, b0, c10, 0, 0, 0);
    }
    #pragma unroll
    for (int r = 0; r < 4; ++r) {
      const int ta = quad * 4 + r, tb = 16 + quad * 4 + r;
      claT[ta * 136 + ct * 16 + l16] = f2us(__expf(c00[r]));
      claT[tb * 136 + ct * 16 + l16] = f2us(__expf(c10[r]));
    }
  }
  __syncthreads();   // B3: claT complete

  // ---- logits = cla @ tm_out; 6 N-tiles over waves 0-5; fused blend epilogue ----
  if (wave < 6) {
    const int nt = wave;
    short8 btm[4];
    #pragma unroll
    for (int ks = 0; ks < 4; ++ks)
      btm[ks] = *reinterpret_cast<const short8*>(
          tmoT + (size_t)(nt * 16 + l16) * NCL_ + ks * 32 + quad * 8);
    f32x4 acc0 = {0.f, 0.f, 0.f, 0.f}, acc1 = {0.f, 0.f, 0.f, 0.f};
    #pragma unroll
    for (int ks = 0; ks < 4; ++ks) {
      const int k0 = ks * 32 + quad * 8;
      short8 a0 = *reinterpret_cast<const short8*>(&claT[l16 * 136 + k0]);
      short8 a1 = *reinterpret_cast<const short8*>(&claT[(16 + l16) * 136 + k0]);
      acc0 = __builtin_amdgcn_mfma_f32_16x16x32_bf16(a0, btm[ks], acc0, 0, 0, 0);
      acc1 = __builtin_amdgcn_mfma_f32_16x16x32_bf16(a1, btm[ks], acc1, 0, 0, 0);
    }
    const int c = nt * 16 + l16;
    #pragma unroll
    for (int r = 0; r < 4; ++r) {
      const int ta = quad * 4 + r, tb = 16 + quad * 4 + r;
      float lg0 = acc0[r], lg1 = acc1[r];
      out[(tok0 + ta) * NC + c] = xr[0][r] + gv * lg0 + (1.f - gv) * sigmoidf_(lg0);
      out[(tok0 + tb) * NC + c] = xr[1][r] + gv * lg1 + (1.f - gv) * sigmoidf_(lg1);
    }
  }
}

extern "C" void kernel_launch(void* const* d_in, const int* in_sizes, int n_in,
                              void* d_out, int out_size, void* d_ws, size_t ws_size,
                              hipStream_t stream) {
  (void)in_sizes; (void)n_in; (void)out_size; (void)ws_size;
  const float* x      = (const float*)d_in[0];
  const float* n1g    = (const float*)d_in[1];
  const float* n1b    = (const float*)d_in[2];
  const float* qkv_w  = (const float*)d_in[3];
  const float* qkv_b  = (const float*)d_in[4];
  const float* proj_w = (const float*)d_in[5];
  const float* proj_b = (const float*)d_in[6];
  const float* n2g    = (const float*)d_in[7];
  const float* n2b    = (const float*)d_in[8];
  const float* fng    = (const float*)d_in[9];
  const float* fnb    = (const float*)d_in[10];
  const float* pin_w  = (const float*)d_in[11];
  const float* pin_b  = (const float*)d_in[12];
  const float* tm_inc = (const float*)d_in[13];
  const float* tm_out = (const float*)d_in[14];
  const float* gate   = (const float*)d_in[15];

  float* x1 = (float*)d_ws;                         // NTOK*96 f32
  u16* maskb = (u16*)(x1 + (size_t)NTOK * NC);      // 128*768 bf16
  u16* pinwb = maskb + NCL_ * NLIT;                 // 384*96 bf16
  u16* tmoT  = pinwb + HID_ * NC;                   // 96*128 bf16
  u16* qkvwb = tmoT + NC * NCL_;                    // 288*96 bf16
  u16* projwb= qkvwb + 3 * NC * NC;                 // 96*96 bf16

  hipLaunchKernelGGL(k0_prep, dim3(384), dim3(256), 0, stream,
                     tm_inc, pin_w, tm_out, qkv_w, proj_w, maskb, pinwb, tmoT, qkvwb, projwb);
  hipLaunchKernelGGL(k2_attn, dim3(NWIN), dim3(256), 0, stream,
                     x, n1g, n1b, qkvwb, qkv_b, projwb, proj_b, x1);
  hipLaunchKernelGGL(k4_ffn, dim3(NTOK / 32), dim3(512), 0, stream,
                     x1, n2g, n2b, fng, fnb, pinwb, pin_b, maskb, tmoT, gate, (float*)d_out);
}

// Round 14
// 193.736 us; speedup vs baseline: 1.2174x; 1.0015x over previous
//
#include <hip/hip_runtime.h>

// ---- problem constants (B,H0,W0,C)=(16,56,56,96), NH=3, WS=7, SS=3, HID=384, NCL=128 ----
#define NB 16
#define NHH 56
#define NWW 56
#define NC 96
#define NL (NHH*NWW)          // 3136
#define NTOK (NB*NL)          // 50176
#define WSZ 7
#define NT 49                 // tokens per window
#define SSH 3
#define NWIN 1024             // 16 * 8 * 8
#define HDIM 32
#define HID_ 384
#define NCL_ 128
#define NLIT 768
#define EPS_ 1e-6f
#define LOG_EPS -13.815510558f

typedef unsigned short u16;
typedef unsigned int   u32;
typedef __attribute__((ext_vector_type(8))) short short8;   // 8 bf16 (4 VGPRs)
typedef __attribute__((ext_vector_type(4))) float f32x4;    // MFMA C/D

__device__ __forceinline__ float us2f(u16 u) {
  union { u32 u; float f; } x; x.u = ((u32)u) << 16; return x.f;
}
__device__ __forceinline__ u16 f2us(float f) {   // RNE float->bf16
  union { float f; u32 u; } x; x.f = f;
  u32 lsb = (x.u >> 16) & 1u;
  return (u16)((x.u + 0x7fffu + lsb) >> 16);
}
__device__ __forceinline__ float sigmoidf_(float x) { return 1.f / (1.f + __expf(-x)); }

// ---------------- K0: build bf16 constants ----------------
__global__ __launch_bounds__(256) void k0_prep(const float* __restrict__ tm_inc,
                                               const float* __restrict__ pin_w,
                                               const float* __restrict__ tm_out,
                                               const float* __restrict__ qkv_w,
                                               const float* __restrict__ proj_w,
                                               u16* __restrict__ maskb,
                                               u16* __restrict__ pinwb,
                                               u16* __restrict__ tmoT,
                                               u16* __restrict__ qkvwb,
                                               u16* __restrict__ projwb) {
  int idx = blockIdx.x * 256 + threadIdx.x;
  if (idx < NCL_ * NLIT)
    maskb[idx] = (tm_inc[idx] > 0.f) ? (u16)0x3F80 : (u16)0;
  if (idx < HID_ * NC)
    pinwb[idx] = f2us(pin_w[idx]);
  if (idx < NC * NCL_) {
    int c = idx / NCL_, k = idx - c * NCL_;
    tmoT[idx] = f2us(tm_out[(size_t)k * NC + c]);
  }
  if (idx < 3 * NC * NC)
    qkvwb[idx] = f2us(qkv_w[idx]);
  if (idx < NC * NC)
    projwb[idx] = f2us(proj_w[idx]);
}

// ---------------- K2: LN1 + window gather + MFMA attention + proj + residual scatter ----------------
// One block = one window. 4 waves; wave w owns query rows 16w..16w+15.
// syb triple-duty: LN1'd y -> q (QKV phase, wave-own rows) -> attn-out (PV, wave-own rows).
// NO barrier after LN: wave w's A-frag rows are written by wave w's own LN threads
// (tids 64w..64w+63 <-> tokens/rows 16w..16w+15; zero-rows 49-63 by wave 3, read by wave 3).
// LDS: syb 13,312 + sk 13,312 + svT 13,824 + sp 9,216 = 49,664 B -> 3 blocks/CU.
__global__ __launch_bounds__(256) void k2_attn(const float* __restrict__ x,
                                               const float* __restrict__ n1g,
                                               const float* __restrict__ n1b,
                                               const u16* __restrict__ qkvwb,
                                               const float* __restrict__ qkv_b,
                                               const u16* __restrict__ projwb,
                                               const float* __restrict__ proj_b,
                                               float* __restrict__ x1) {
  __shared__ __align__(16) u16 syb[64 * 104];
  __shared__ __align__(16) u16 sk [64 * 104];
  __shared__ __align__(16) u16 svT[96 * 72];
  __shared__ __align__(16) u16 sp [4 * 16 * 72];
  const int tid  = threadIdx.x;
  const int wave = tid >> 6;
  const int lane = tid & 63;
  const int l16  = lane & 15;
  const int quad = lane >> 4;
  const int win  = blockIdx.x;
  const int t0   = wave * 16;
  const int bb = win >> 6, wl = win & 63;
  const int hbase = (wl >> 3) * WSZ, wbase = (wl & 7) * WSZ;

  // ---- LN1 head: 4 threads per token; gather from x with inverse global roll ----
  {
    const int t = tid >> 2, s = tid & 3;
    if (t < NT) {
      int hp = hbase + t / WSZ, wp = wbase + t % WSZ;
      int h = hp + SSH; if (h >= NHH) h -= NHH;
      int w = wp + SSH; if (w >= NWW) w -= NWW;
      const float* xp = x + ((size_t)bb * NL + (size_t)h * NWW + w) * NC;
      float4 v[6];
      float sum = 0.f;
      #pragma unroll
      for (int k = 0; k < 6; ++k) {
        v[k] = *reinterpret_cast<const float4*>(xp + s * 4 + k * 16);
        sum += v[k].x + v[k].y + v[k].z + v[k].w;
      }
      sum += __shfl_xor(sum, 1); sum += __shfl_xor(sum, 2);
      float mean = sum * (1.f / 96.f);
      float ssq = 0.f;
      #pragma unroll
      for (int k = 0; k < 6; ++k) {
        float d0 = v[k].x - mean, d1 = v[k].y - mean;
        float d2 = v[k].z - mean, d3 = v[k].w - mean;
        ssq += d0 * d0 + d1 * d1 + d2 * d2 + d3 * d3;
      }
      ssq += __shfl_xor(ssq, 1); ssq += __shfl_xor(ssq, 2);
      float rstd = rsqrtf(ssq * (1.f / 96.f) + 1e-5f);
      #pragma unroll
      for (int k = 0; k < 6; ++k) {
        int c = s * 4 + k * 16;
        const float4 g4 = *reinterpret_cast<const float4*>(n1g + c);
        const float4 b4 = *reinterpret_cast<const float4*>(n1b + c);
        syb[t * 104 + c + 0] = f2us((v[k].x - mean) * rstd * g4.x + b4.x);
        syb[t * 104 + c + 1] = f2us((v[k].y - mean) * rstd * g4.y + b4.y);
        syb[t * 104 + c + 2] = f2us((v[k].z - mean) * rstd * g4.z + b4.z);
        syb[t * 104 + c + 3] = f2us((v[k].w - mean) * rstd * g4.w + b4.w);
      }
    } else {
      #pragma unroll
      for (int k = 0; k < 6; ++k) {
        int c = s * 4 + k * 16;
        syb[t * 104 + c + 0] = 0; syb[t * 104 + c + 1] = 0;
        syb[t * 104 + c + 2] = 0; syb[t * 104 + c + 3] = 0;
      }
    }
  }
  // NO __syncthreads() here: A-frag rows below are wave-own (see header comment);
  // compiler-inserted lgkmcnt ordering covers the same-wave write->read dependency.

  // ---- QKV: M=64, N=288 (18 tiles), K=96 (3 steps); depth-4 B-frag ring.
  //      q is written back into syb (wave-own rows). ----
  {
    short8 afr[3];
    #pragma unroll
    for (int ks = 0; ks < 3; ++ks)
      afr[ks] = *reinterpret_cast<const short8*>(&syb[(t0 + l16) * 104 + quad * 8 + ks * 32]);
    short8 rb[4][3];
    #pragma unroll
    for (int p = 0; p < 4; ++p)
      #pragma unroll
      for (int ks = 0; ks < 3; ++ks)
        rb[p][ks] = *reinterpret_cast<const short8*>(
            qkvwb + (size_t)(p * 16 + l16) * NC + quad * 8 + ks * 32);
    #pragma unroll
    for (int nt = 0; nt < 18; ++nt) {
      const int n0 = nt * 16;
      const float bias = qkv_b[n0 + l16];
      short8 b0 = rb[nt & 3][0], b1 = rb[nt & 3][1], b2 = rb[nt & 3][2];
      if (nt + 4 < 18) {
        #pragma unroll
        for (int ks = 0; ks < 3; ++ks)
          rb[nt & 3][ks] = *reinterpret_cast<const short8*>(
              qkvwb + (size_t)((nt + 4) * 16 + l16) * NC + quad * 8 + ks * 32);
      }
      f32x4 acc = {0.f, 0.f, 0.f, 0.f};
      acc = __builtin_amdgcn_mfma_f32_16x16x32_bf16(afr[0], b0, acc, 0, 0, 0);
      acc = __builtin_amdgcn_mfma_f32_16x16x32_bf16(afr[1], b1, acc, 0, 0, 0);
      acc = __builtin_amdgcn_mfma_f32_16x16x32_bf16(afr[2], b2, acc, 0, 0, 0);
      const int part = nt / 6;                 // 0=q 1=k 2=v
      const int oc = n0 - part * 96 + l16;
      if (part < 2) {
        u16* dst = (part == 0) ? syb : sk;     // q overwrites y in wave-own rows
        #pragma unroll
        for (int r = 0; r < 4; ++r)
          dst[(t0 + quad * 4 + r) * 104 + oc] = f2us(acc[r] + bias);
      } else {
        #pragma unroll
        for (int r = 0; r < 4; ++r)
          svT[oc * 72 + (t0 + quad * 4 + r)] = f2us(acc[r] + bias);
      }
    }
  }
  __syncthreads();   // B2: k/v (cross-wave) must be complete

  // ---- all-head scores first (12 independent MFMAs, max MLP), then per-head softmax+PV ----
  u16* spw = sp + wave * 16 * 72;
  const float sscale = 0.17677669529663687f;
  short8 qf[3];
  f32x4 s[3][4];
  #pragma unroll
  for (int h = 0; h < 3; ++h)
    qf[h] = *reinterpret_cast<const short8*>(&syb[(t0 + l16) * 104 + h * HDIM + quad * 8]);
  #pragma unroll
  for (int h = 0; h < 3; ++h) {
    const int d0 = h * HDIM;
    #pragma unroll
    for (int nt = 0; nt < 4; ++nt) {
      short8 kf = *reinterpret_cast<const short8*>(&sk[(nt * 16 + l16) * 104 + d0 + quad * 8]);
      f32x4 a = {0.f, 0.f, 0.f, 0.f};
      s[h][nt] = __builtin_amdgcn_mfma_f32_16x16x32_bf16(qf[h], kf, a, 0, 0, 0);
    }
  }
  #pragma unroll
  for (int h = 0; h < 3; ++h) {
    const int d0 = h * HDIM;
    #pragma unroll
    for (int nt = 0; nt < 4; ++nt)
      #pragma unroll
      for (int r = 0; r < 4; ++r) s[h][nt][r] *= sscale;
    if (l16 >= 1) {                       // key col 48+l16 >= 49 -> mask
      #pragma unroll
      for (int r = 0; r < 4; ++r) s[h][3][r] = -1e30f;
    }
    #pragma unroll
    for (int r = 0; r < 4; ++r) {
      float m = fmaxf(fmaxf(s[h][0][r], s[h][1][r]), fmaxf(s[h][2][r], s[h][3][r]));
      #pragma unroll
      for (int off = 8; off > 0; off >>= 1) m = fmaxf(m, __shfl_xor(m, off, 16));
      float e0 = __expf(s[h][0][r] - m), e1 = __expf(s[h][1][r] - m);
      float e2 = __expf(s[h][2][r] - m), e3 = __expf(s[h][3][r] - m);
      float sum = e0 + e1 + e2 + e3;
      #pragma unroll
      for (int off = 8; off > 0; off >>= 1) sum += __shfl_xor(sum, off, 16);
      float inv = 1.f / sum;
      const int row = quad * 4 + r;
      spw[row * 72 +      l16] = f2us(e0 * inv);
      spw[row * 72 + 16 + l16] = f2us(e1 * inv);
      spw[row * 72 + 32 + l16] = f2us(e2 * inv);
      spw[row * 72 + 48 + l16] = f2us(e3 * inv);
    }
    short8 pa[2];
    pa[0] = *reinterpret_cast<const short8*>(&spw[l16 * 72 + quad * 8]);
    pa[1] = *reinterpret_cast<const short8*>(&spw[l16 * 72 + 32 + quad * 8]);
    #pragma unroll
    for (int nt = 0; nt < 2; ++nt) {
      const int c0 = d0 + nt * 16;
      f32x4 acc = {0.f, 0.f, 0.f, 0.f};
      #pragma unroll
      for (int ks = 0; ks < 2; ++ks) {
        short8 vb = *reinterpret_cast<const short8*>(&svT[(c0 + l16) * 72 + ks * 32 + quad * 8]);
        acc = __builtin_amdgcn_mfma_f32_16x16x32_bf16(pa[ks], vb, acc, 0, 0, 0);
      }
      #pragma unroll
      for (int r = 0; r < 4; ++r)
        syb[(t0 + quad * 4 + r) * 104 + c0 + l16] = f2us(acc[r]);
    }
  }

  // ---- proj: N=96 (6 tiles), K=96 (3 steps); prefetched residuals + depth-2 B ring ----
  {
    short8 aa[3];
    #pragma unroll
    for (int ks = 0; ks < 3; ++ks)
      aa[ks] = *reinterpret_cast<const short8*>(&syb[(t0 + l16) * 104 + quad * 8 + ks * 32]);

    size_t tokr[4]; bool tval[4];
    #pragma unroll
    for (int r = 0; r < 4; ++r) {
      const int t = t0 + quad * 4 + r;
      tval[r] = (t < NT);
      int rr = t / WSZ + SSH; if (rr >= WSZ) rr -= WSZ;
      int qq = t % WSZ + SSH; if (qq >= WSZ) qq -= WSZ;
      tokr[r] = (size_t)bb * NL + (size_t)(hbase + rr) * NWW + (wbase + qq);
    }
    float xv[6][4];
    #pragma unroll
    for (int nt = 0; nt < 6; ++nt)
      #pragma unroll
      for (int r = 0; r < 4; ++r)
        xv[nt][r] = tval[r] ? x[tokr[r] * NC + nt * 16 + l16] : 0.f;

    short8 pbr[2][3];
    #pragma unroll
    for (int ks = 0; ks < 3; ++ks)
      pbr[0][ks] = *reinterpret_cast<const short8*>(
          projwb + (size_t)l16 * NC + quad * 8 + ks * 32);
    #pragma unroll
    for (int nt = 0; nt < 6; ++nt) {
      const int n0 = nt * 16;
      const float pb = proj_b[n0 + l16];
      short8 b0 = pbr[nt & 1][0], b1 = pbr[nt & 1][1], b2 = pbr[nt & 1][2];
      if (nt + 1 < 6) {
        #pragma unroll
        for (int ks = 0; ks < 3; ++ks)
          pbr[(nt + 1) & 1][ks] = *reinterpret_cast<const short8*>(
              projwb + (size_t)((nt + 1) * 16 + l16) * NC + quad * 8 + ks * 32);
      }
      f32x4 acc = {0.f, 0.f, 0.f, 0.f};
      acc = __builtin_amdgcn_mfma_f32_16x16x32_bf16(aa[0], b0, acc, 0, 0, 0);
      acc = __builtin_amdgcn_mfma_f32_16x16x32_bf16(aa[1], b1, acc, 0, 0, 0);
      acc = __builtin_amdgcn_mfma_f32_16x16x32_bf16(aa[2], b2, acc, 0, 0, 0);
      #pragma unroll
      for (int r = 0; r < 4; ++r) {
        if (tval[r])
          x1[tokr[r] * NC + n0 + l16] = xv[nt][r] + acc[r] + pb;
      }
    }
  }
}

// ---------------- K4: double-LN + TM-FFN via MFMA; 32 tokens/block, 8 waves (512 thr) ----------------
// (unchanged from round 12/13)
__global__ __launch_bounds__(512) void k4_ffn(const float* __restrict__ x1,
                                              const float* __restrict__ g2,
                                              const float* __restrict__ b2,
                                              const float* __restrict__ gf,
                                              const float* __restrict__ bf,
                                              const u16* __restrict__ pinwb,
                                              const float* __restrict__ pin_b,
                                              const u16* __restrict__ maskb,
                                              const u16* __restrict__ tmoT,
                                              const float* __restrict__ gate,
                                              float* __restrict__ out) {
  __shared__ __align__(16) u16 lit[32 * 776];   // bf16 log-literals [t][j]
  __shared__ __align__(16) u16 su[32 * 136];    // union: szb (32x104, dies early) / claT (32x136)
  u16* szb  = su;
  u16* claT = su;
  const int tid  = threadIdx.x;
  const int wave = tid >> 6;
  const int lane = tid & 63;
  const int l16  = lane & 15;
  const int quad = lane >> 4;
  const size_t tok0 = (size_t)blockIdx.x * 32;

  // ---- LN(LN(x1)) head: 16 lanes per token, 6 channels each (float2 x 3) ----
  {
    const int t = tid >> 4, s = tid & 15;
    const float* xp = x1 + (tok0 + t) * NC;
    float2 v[3];
    float sum = 0.f;
    #pragma unroll
    for (int k = 0; k < 3; ++k) {
      const int c = s * 2 + k * 32;
      v[k] = *reinterpret_cast<const float2*>(xp + c);
      sum += v[k].x + v[k].y;
    }
    #pragma unroll
    for (int off = 8; off > 0; off >>= 1) sum += __shfl_xor(sum, off, 16);
    const float mean = sum * (1.f / 96.f);
    float ssq = 0.f;
    #pragma unroll
    for (int k = 0; k < 3; ++k) {
      float d0 = v[k].x - mean, d1 = v[k].y - mean;
      ssq += d0 * d0 + d1 * d1;
    }
    #pragma unroll
    for (int off = 8; off > 0; off >>= 1) ssq += __shfl_xor(ssq, off, 16);
    const float rstd = rsqrtf(ssq * (1.f / 96.f) + 1e-5f);
    float tv[6];
    float sum2 = 0.f;
    #pragma unroll
    for (int k = 0; k < 3; ++k) {
      const int c = s * 2 + k * 32;
      const float2 gg = *reinterpret_cast<const float2*>(g2 + c);
      const float2 bb = *reinterpret_cast<const float2*>(b2 + c);
      tv[2 * k]     = (v[k].x - mean) * rstd * gg.x + bb.x;
      tv[2 * k + 1] = (v[k].y - mean) * rstd * gg.y + bb.y;
      sum2 += tv[2 * k] + tv[2 * k + 1];
    }
    #pragma unroll
    for (int off = 8; off > 0; off >>= 1) sum2 += __shfl_xor(sum2, off, 16);
    const float mean2 = sum2 * (1.f / 96.f);
    float ssq2 = 0.f;
    #pragma unroll
    for (int k = 0; k < 3; ++k) {
      float d0 = tv[2 * k] - mean2, d1 = tv[2 * k + 1] - mean2;
      ssq2 += d0 * d0 + d1 * d1;
    }
    #pragma unroll
    for (int off = 8; off > 0; off >>= 1) ssq2 += __shfl_xor(ssq2, off, 16);
    const float rstd2 = rsqrtf(ssq2 * (1.f / 96.f) + 1e-5f);
    #pragma unroll
    for (int k = 0; k < 3; ++k) {
      const int c = s * 2 + k * 32;
      const float2 gg = *reinterpret_cast<const float2*>(gf + c);
      const float2 bb = *reinterpret_cast<const float2*>(bf + c);
      u16 lo = f2us((tv[2 * k]     - mean2) * rstd2 * gg.x + bb.x);
      u16 hi = f2us((tv[2 * k + 1] - mean2) * rstd2 * gg.y + bb.y);
      *reinterpret_cast<u32*>(&szb[t * 104 + c]) = (u32)lo | ((u32)hi << 16);
    }
  }
  __syncthreads();   // B1: szb complete

  const float gv = sigmoidf_(gate[0]);

  // A-frags for both pin M-tiles (szb dies after these loads; claT reuses su after B2)
  short8 a_pin[2][3];
  #pragma unroll
  for (int mt = 0; mt < 2; ++mt)
    #pragma unroll
    for (int ks = 0; ks < 3; ++ks)
      a_pin[mt][ks] = *reinterpret_cast<const short8*>(
          &szb[(mt * 16 + l16) * 104 + quad * 8 + ks * 32]);

  // ---- pin gemm: wave w -> N-tiles [3w,3w+3); ALL 9 B-frags loaded up front; 2 MFMA per B-frag;
  //      softplus literals: log(sig(a)) = a - sp, log(1-sig(a)) = -sp ----
  {
    float pbias[3];
    #pragma unroll
    for (int i = 0; i < 3; ++i) pbias[i] = pin_b[(wave * 3 + i) * 16 + l16];
    short8 pb[3][3];
    #pragma unroll
    for (int i = 0; i < 3; ++i)
      #pragma unroll
      for (int ks = 0; ks < 3; ++ks)
        pb[i][ks] = *reinterpret_cast<const short8*>(
            pinwb + (size_t)((wave * 3 + i) * 16 + l16) * NC + quad * 8 + ks * 32);
    #pragma unroll
    for (int i = 0; i < 3; ++i) {
      f32x4 acc0 = {0.f, 0.f, 0.f, 0.f}, acc1 = {0.f, 0.f, 0.f, 0.f};
      acc0 = __builtin_amdgcn_mfma_f32_16x16x32_bf16(a_pin[0][0], pb[i][0], acc0, 0, 0, 0);
      acc1 = __builtin_amdgcn_mfma_f32_16x16x32_bf16(a_pin[1][0], pb[i][0], acc1, 0, 0, 0);
      acc0 = __builtin_amdgcn_mfma_f32_16x16x32_bf16(a_pin[0][1], pb[i][1], acc0, 0, 0, 0);
      acc1 = __builtin_amdgcn_mfma_f32_16x16x32_bf16(a_pin[1][1], pb[i][1], acc1, 0, 0, 0);
      acc0 = __builtin_amdgcn_mfma_f32_16x16x32_bf16(a_pin[0][2], pb[i][2], acc0, 0, 0, 0);
      acc1 = __builtin_amdgcn_mfma_f32_16x16x32_bf16(a_pin[1][2], pb[i][2], acc1, 0, 0, 0);
      const int o = (wave * 3 + i) * 16 + l16;
      const float pbv = pbias[i];
      #pragma unroll
      for (int r = 0; r < 4; ++r) {
        const float a0 = acc0[r] + pbv;
        const float sp0 = fmaxf(a0, 0.f) + __logf(1.f + __expf(-fabsf(a0)));
        const float a1 = acc1[r] + pbv;
        const float sp1 = fmaxf(a1, 0.f) + __logf(1.f + __expf(-fabsf(a1)));
        const int ta = quad * 4 + r, tb = 16 + quad * 4 + r;
        lit[ta * 776 + o]       = f2us(fmaxf(a0 - sp0, LOG_EPS));
        lit[ta * 776 + 384 + o] = f2us(fmaxf(-sp0, LOG_EPS));
        lit[tb * 776 + o]       = f2us(fmaxf(a1 - sp1, LOG_EPS));
        lit[tb * 776 + 384 + o] = f2us(fmaxf(-sp1, LOG_EPS));
      }
    }
  }
  __syncthreads();   // B2: lit complete (also fences a_pin/szb reads vs claT writes)

  // prefetch epilogue residuals (hidden behind the clause gemm)
  float xr[2][4];
  if (wave < 6) {
    const int c = wave * 16 + l16;
    #pragma unroll
    for (int r = 0; r < 4; ++r) {
      xr[0][r] = x1[(tok0 + quad * 4 + r) * NC + c];
      xr[1][r] = x1[(tok0 + 16 + quad * 4 + r) * NC + c];
    }
  }

  // ---- clause gemm: wave w -> clause tile w; depth-8 B ring; 2 MFMA per B-frag ----
  {
    const int ct = wave;
    const u16* bp0 = maskb + (size_t)(ct * 16 + l16) * NLIT + quad * 8;
    short8 rb0[8];
    #pragma unroll
    for (int p = 0; p < 8; ++p)
      rb0[p] = *reinterpret_cast<const short8*>(bp0 + p * 32);
    f32x4 c00 = {0.f, 0.f, 0.f, 0.f}, c10 = {0.f, 0.f, 0.f, 0.f};
    #pragma unroll
    for (int ks = 0; ks < 24; ++ks) {
      const int k0 = ks * 32 + quad * 8;
      short8 a0 = *reinterpret_cast<const short8*>(&lit[l16 * 776 + k0]);
      short8 a1 = *reinterpret_cast<const short8*>(&lit[(16 + l16) * 776 + k0]);
      short8 b0 = rb0[ks & 7];
      if (ks + 8 < 24)
        rb0[ks & 7] = *reinterpret_cast<const short8*>(bp0 + (ks + 8) * 32);
      c00 = __builtin_amdgcn_mfma_f32_16x16x32_bf16(a0, b0, c00, 0, 0, 0);
      c10 = __builtin_amdgcn_mfma_f32_16x16x32_bf16(a1, b0, c10, 0, 0, 0);
    }
    #pragma unroll
    for (int r = 0; r < 4; ++r) {
      const int ta = quad * 4 + r, tb = 16 + quad * 4 + r;
      claT[ta * 136 + ct * 16 + l16] = f2us(__expf(c00[r]));
      claT[tb * 136 + ct * 16 + l16] = f2us(__expf(c10[r]));
    }
  }
  __syncthreads();   // B3: claT complete

  // ---- logits = cla @ tm_out; 6 N-tiles over waves 0-5; fused blend epilogue ----
  if (wave < 6) {
    const int nt = wave;
    short8 btm[4];
    #pragma unroll
    for (int ks = 0; ks < 4; ++ks)
      btm[ks] = *reinterpret_cast<const short8*>(
          tmoT + (size_t)(nt * 16 + l16) * NCL_ + ks * 32 + quad * 8);
    f32x4 acc0 = {0.f, 0.f, 0.f, 0.f}, acc1 = {0.f, 0.f, 0.f, 0.f};
    #pragma unroll
    for (int ks = 0; ks < 4; ++ks) {
      const int k0 = ks * 32 + quad * 8;
      short8 a0 = *reinterpret_cast<const short8*>(&claT[l16 * 136 + k0]);
      short8 a1 = *reinterpret_cast<const short8*>(&claT[(16 + l16) * 136 + k0]);
      acc0 = __builtin_amdgcn_mfma_f32_16x16x32_bf16(a0, btm[ks], acc0, 0, 0, 0);
      acc1 = __builtin_amdgcn_mfma_f32_16x16x32_bf16(a1, btm[ks], acc1, 0, 0, 0);
    }
    const int c = nt * 16 + l16;
    #pragma unroll
    for (int r = 0; r < 4; ++r) {
      const int ta = quad * 4 + r, tb = 16 + quad * 4 + r;
      float lg0 = acc0[r], lg1 = acc1[r];
      out[(tok0 + ta) * NC + c] = xr[0][r] + gv * lg0 + (1.f - gv) * sigmoidf_(lg0);
      out[(tok0 + tb) * NC + c] = xr[1][r] + gv * lg1 + (1.f - gv) * sigmoidf_(lg1);
    }
  }
}

extern "C" void kernel_launch(void* const* d_in, const int* in_sizes, int n_in,
                              void* d_out, int out_size, void* d_ws, size_t ws_size,
                              hipStream_t stream) {
  (void)in_sizes; (void)n_in; (void)out_size; (void)ws_size;
  const float* x      = (const float*)d_in[0];
  const float* n1g    = (const float*)d_in[1];
  const float* n1b    = (const float*)d_in[2];
  const float* qkv_w  = (const float*)d_in[3];
  const float* qkv_b  = (const float*)d_in[4];
  const float* proj_w = (const float*)d_in[5];
  const float* proj_b = (const float*)d_in[6];
  const float* n2g    = (const float*)d_in[7];
  const float* n2b    = (const float*)d_in[8];
  const float* fng    = (const float*)d_in[9];
  const float* fnb    = (const float*)d_in[10];
  const float* pin_w  = (const float*)d_in[11];
  const float* pin_b  = (const float*)d_in[12];
  const float* tm_inc = (const float*)d_in[13];
  const float* tm_out = (const float*)d_in[14];
  const float* gate   = (const float*)d_in[15];

  float* x1 = (float*)d_ws;                         // NTOK*96 f32
  u16* maskb = (u16*)(x1 + (size_t)NTOK * NC);      // 128*768 bf16
  u16* pinwb = maskb + NCL_ * NLIT;                 // 384*96 bf16
  u16* tmoT  = pinwb + HID_ * NC;                   // 96*128 bf16
  u16* qkvwb = tmoT + NC * NCL_;                    // 288*96 bf16
  u16* projwb= qkvwb + 3 * NC * NC;                 // 96*96 bf16

  hipLaunchKernelGGL(k0_prep, dim3(384), dim3(256), 0, stream,
                     tm_inc, pin_w, tm_out, qkv_w, proj_w, maskb, pinwb, tmoT, qkvwb, projwb);
  hipLaunchKernelGGL(k2_attn, dim3(NWIN), dim3(256), 0, stream,
                     x, n1g, n1b, qkvwb, qkv_b, projwb, proj_b, x1);
  hipLaunchKernelGGL(k4_ffn, dim3(NTOK / 32), dim3(512), 0, stream,
                     x1, n2g, n2b, fng, fnb, pinwb, pin_b, maskb, tmoT, gate, (float*)d_out);
}